// Round 10
// baseline (464.503 us; speedup 1.0000x reference)
//
#include <hip/hip_runtime.h>
#include <hip/hip_bf16.h>

#define BATCH 8192
#define IN_DIM 64
#define HID 1024
#define KTOT 1088   // HID + IN_DIM (fused K; weights laid out [n][KTOT])
#define NGATES 4096 // 4*HID, column c = 64*G + 16*g + q -> gate g of h=16*G+q
#define OMID 128
#define NP 256      // packed P rows (W1 0..127, W_halt 128, zeros)
#define MAX_ITER 8

#define TM 128
#define TN 128
#define TK 64
#define TMF 16      // midfin m-tile (R21: 16 rows -> 512 tiles = 2 blocks/CU)
#define NBH 144     // midfin Bs rows: 128 W1 + 16 (W_halt @128 + zeros)
#define TAILB 64    // tail_k blocks: few enough that a device barrier is cheap

typedef __attribute__((ext_vector_type(8))) short short8;
typedef __attribute__((ext_vector_type(4))) float float4v;
typedef __attribute__((ext_vector_type(4))) float float4f;
typedef __attribute__((ext_vector_type(4))) short short4v;

__device__ __forceinline__ float bf2f(short s) {
    union { float f; unsigned u; } v; v.u = ((unsigned)(unsigned short)s) << 16; return v.f;
}
__device__ __forceinline__ short f2bf(float f) {
    union { float f; unsigned u; } v; v.f = f;
    unsigned r = v.u + 0x7fff + ((v.u >> 16) & 1);  // round-to-nearest-even
    return (short)(r >> 16);
}
__device__ __forceinline__ float sigmoidf_(float x) {
    float xc = fminf(fmaxf(x, -30.f), 30.f);
    return 1.f / (1.f + __expf(-xc));
}
__device__ __forceinline__ float tanhf_(float x) {
    float xc = fminf(fmaxf(x, -15.f), 15.f);
    float e = __expf(2.f * xc);
    return (e - 1.f) / (e + 1.f);
}
__device__ __forceinline__ int aload(const int* p) {
    return __hip_atomic_load((int*)p, __ATOMIC_RELAXED, __HIP_MEMORY_SCOPE_AGENT);
}
__device__ __forceinline__ void astore(int* p, int v) {
    __hip_atomic_store(p, v, __ATOMIC_RELAXED, __HIP_MEMORY_SCOPE_AGENT);
}

// 64-block generation barrier (R8-verified; R5/R7/R11: ANY wider barrier
// pays 50-100us in cross-XCD L2 invalidate traffic). RELAXED polling by one
// lane per block with s_sleep; fences only at the crossing points.
__device__ __forceinline__ void gbar(int* bar, int phase, int tid) {
    __syncthreads();
    if (tid == 0) {
        __threadfence();
        __hip_atomic_fetch_add(bar, 1, __ATOMIC_ACQ_REL, __HIP_MEMORY_SCOPE_AGENT);
        while (aload(bar) < TAILB * phase)
            __builtin_amdgcn_s_sleep(8);
        __threadfence();
    }
    __syncthreads();
}

// Shared epilogue: fused LSTM cell update for one 128-row m-tile's
// accumulators (4-wave 128^2 layout; used by gates_k and gates_tile).
// first=1 (t==0): cell is write-only (c = i*cg == f*0 + i*cg bit-exactly),
// so cell never needs zero-init and t=0 skips the 33.6MB cell read.
__device__ __forceinline__ void gates_epilogue(
    const float4v (&acc)[4][4], int m0, int bx, int wave, int lane, int first,
    const float* __restrict__ bias_g, float* __restrict__ cell,
    short* __restrict__ Sout, const int* __restrict__ ridx, int n_act)
{
    const int wm = wave & 1, wn = wave >> 1;
    const int colq = lane & 15, q = lane >> 4;
    const int G = bx * 2 + wn;   // 64-col group = 16 hidden units
    const int h = G * 16 + colq;
    const float bi  = bias_g[G * 64 +  0 + colq];
    const float bff = bias_g[G * 64 + 16 + colq];
    const float bc  = bias_g[G * 64 + 32 + colq];
    const float bo  = bias_g[G * 64 + 48 + colq];
#pragma unroll
    for (int i = 0; i < 4; ++i) {
        const int pbase = m0 + wm * 64 + i * 16 + q * 4;
#pragma unroll
        for (int r = 0; r < 4; ++r) {
            const int pos = pbase + r;
            if (pos < n_act) {
                const int row = ridx[pos];
                const float ig = sigmoidf_(acc[i][0][r] + bi);
                const float fg = sigmoidf_(acc[i][1][r] + bff);
                const float cg = tanhf_(acc[i][2][r] + bc);
                const float og = sigmoidf_(acc[i][3][r] + bo);
                const size_t ci = (size_t)row * HID + h;
                const float c = first ? (ig * cg) : (fg * cell[ci] + ig * cg);
                cell[ci] = c;
                Sout[(size_t)row * HID + h] = f2bf(og * tanhf_(c));
            }
        }
    }
}

// Gates GEMM, R22: MULTI-BLOCK-PER-CU structure. R13-R19 showed the 256^2
// 8-wave/1-block form is schedule-insensitive at 575-627 TF: 128KB LDS +
// 232 VGPR/wave pin the CU to ONE 8-wave barrier group -> every drain
// stalls the whole CU with no independent work to absorb it. R22 breaks
// the lockstep: 128x128 tile, 4 waves (2Mx2N, 64x64/wave, acc=64 VGPR),
// B-OPERAND READ DIRECTLY FROM GLOBAL (L2-resident: XCD-rectangle swizzle
// gives each XCD 4 B-panels = 1.1MB; lanes (colq,q) form 64B segments;
// B-loads are wave-private -> not barrier-coupled). LDS = A-only dbuf
// 2x16KB -> 3-4 independent blocks/CU = 12-16 waves/CU (vs 8): while one
// block drains its barrier, others compute. L2 traffic unchanged (staging
// also read L2); LDS reads drop 192->64KB per K-step-equivalent.
// A-side: split layout (S + XB tail chunk), XOR swizzle, 2-phase dbuf
// (stage(ki+1) issued before compute(ki)) — all R14/R18-verified.
__global__ __launch_bounds__(256) void gates_k(
    const short* __restrict__ S, const short* __restrict__ XB,
    const short* __restrict__ B,
    const float* __restrict__ bias_g, int nK, int hidK, int first,
    float* __restrict__ cell, short* __restrict__ Sout,
    const int* __restrict__ ridx, const int* __restrict__ cnt, int t)
{
    __shared__ short As[2][TM * TK];   // 2 x 16 KiB (A only)
    const int n_act = cnt[t];
    const int tid  = threadIdx.x;
    const int wave = tid >> 6, lane = tid & 63;
    const int wm = wave & 1, wn = wave >> 1;
    const int colq = lane & 15, q = lane >> 4;
    const int lrow8 = lane >> 3;
    const int lk    = (((lane & 7) ^ lrow8) * 8);   // pre-swizzled source offset
    const int xq = colq & 7;

    // XCD-rectangle swizzle (grid is 32 x 64 for all gates_k launches):
    // xcd = lin&7 (hw round-robin); each XCD gets 4 consecutive B-panels
    // (bx = xcd*4 + slot&3 -> 1.1MB, L2-resident) and all m-tiles.
    int bx, byS;
    {
        const int lin  = (int)blockIdx.x + 32 * (int)blockIdx.y;
        const int xcd  = lin & 7;
        const int slot = lin >> 3;         // 0 .. 32*64/8-1
        bx  = xcd * 4 + (slot & 3);
        byS = slot >> 2;                   // 0..63
    }
    const int n0 = bx * TN;

    // per-lane B base: row rb = n0 + wn*64 + colq, k-chunk q*8 (+c2*32)
    const short* Bg = B + (size_t)(n0 + wn * 64 + colq) * KTOT + q * 8;

    // k0-invariant LDS read offsets (row&7 == colq&7 = xq for all i)
    int aoff[4][2];
#pragma unroll
    for (int i = 0; i < 4; ++i) {
        const int Ra = wm * 64 + i * 16 + colq;
#pragma unroll
        for (int c2 = 0; c2 < 2; ++c2)
            aoff[i][c2] = Ra * TK + (((q + 4 * c2) ^ xq) << 3);
    }

    for (int by = byS; by * TM < n_act; by += 64) {
        const int m0 = by * TM;

        // per-thread staged rows: wave*32 + it*8 + lrow8
        int rows_[4];
#pragma unroll
        for (int it = 0; it < 4; ++it)
            rows_[it] = ridx[m0 + wave * 32 + it * 8 + lrow8];

        float4v acc[4][4];
#pragma unroll
        for (int i = 0; i < 4; ++i)
#pragma unroll
            for (int j = 0; j < 4; ++j) acc[i][j] = (float4v)0.f;

        auto stage = [&](int ki, int buf) {     // A only: 4 loads/thread
            const int kk = ki * TK;
            const bool fromS = (kk < hidK);     // kernel-uniform branch
#pragma unroll
            for (int it = 0; it < 4; ++it) {
                const int dst = (wave * 32 + it * 8) * TK;
                const short* sa = fromS
                    ? (S  + (size_t)rows_[it] * HID    + kk + lk)
                    : (XB + (size_t)rows_[it] * IN_DIM + lk);
                __builtin_amdgcn_global_load_lds(
                    (const __attribute__((address_space(1))) void*)sa,
                    (__attribute__((address_space(3))) void*)(As[buf] + dst), 16, 0, 0);
            }
        };

        stage(0, 0);
        __syncthreads();   // drains prologue stage

        for (int ki = 0; ki < nK; ++ki) {
            const int cur = ki & 1;
            if (ki + 1 < nK) stage(ki + 1, cur ^ 1);   // issue BEFORE compute
            const short* Ac = As[cur];
            const size_t kk = (size_t)ki * TK;
#pragma unroll
            for (int c2 = 0; c2 < 2; ++c2) {
                short8 af[4], bf[4];
#pragma unroll
                for (int i = 0; i < 4; ++i)
                    af[i] = *(const short8*)(Ac + aoff[i][c2]);
#pragma unroll
                for (int j = 0; j < 4; ++j)
                    bf[j] = *(const short8*)(Bg + (size_t)j * (16 * KTOT) + kk + c2 * 32);
#pragma unroll
                for (int i = 0; i < 4; ++i)
#pragma unroll
                    for (int j = 0; j < 4; ++j)
                        acc[i][j] = __builtin_amdgcn_mfma_f32_16x16x32_bf16(af[i], bf[j], acc[i][j], 0, 0, 0);
            }
            // one barrier per K-step: ds_reads retired via MFMA deps, the
            // A-stage for ki+1 drained by the barrier's vmcnt wait (B loads
            // are wave-private and already consumed by the MFMAs).
            __syncthreads();
        }

        gates_epilogue(acc, m0, bx, wave, lane, first, bias_g, cell, Sout, ridx, n_act);
        // epilogue touches no LDS; last K-step ended in __syncthreads, so
        // the next m-tile's stage(0,0) (if any) is safe.
    }
}

// Single-m-tile gates (R10 form, split-A, 128^2, B via LDS) — tail_k only.
__device__ __forceinline__ void gates_tile(
    short* As, short* Bs, int tid,
    const short* __restrict__ S, const short* __restrict__ XB,
    const short* __restrict__ B,
    const float* __restrict__ bias_g,
    float* __restrict__ cell, short* __restrict__ Sout,
    const int* __restrict__ ridx, int n_act, int m0, int bx)
{
    const int wave = tid >> 6, lane = tid & 63;
    const int wm = wave & 1, wn = wave >> 1;
    const int colq = lane & 15, q = lane >> 4;
    const int lrow8 = lane >> 3;
    const int lk    = (((lane & 7) ^ lrow8) * 8);
    const int n0 = bx * TN;

    int aoff[4][2], boff[4][2];
#pragma unroll
    for (int i = 0; i < 4; ++i) {
        const int Ra = wm * 64 + i * 16 + colq;
        const int Rb = wn * 64 + i * 16 + colq;
#pragma unroll
        for (int c2 = 0; c2 < 2; ++c2) {
            const int C = q + 4 * c2;
            aoff[i][c2] = Ra * TK + ((C ^ (Ra & 7)) << 3);
            boff[i][c2] = Rb * TK + ((C ^ (Rb & 7)) << 3);
        }
    }

    float4v acc[4][4];
#pragma unroll
    for (int i = 0; i < 4; ++i)
#pragma unroll
        for (int j = 0; j < 4; ++j) acc[i][j] = (float4v)0.f;

    const short* gaS[4];
    const short* gaX[4];
    const short* gb[4];
#pragma unroll
    for (int it = 0; it < 4; ++it) {
        const int rr = (wave * 4 + it) * 8;
        const int r0 = ridx[m0 + rr + lrow8];
        gaS[it] = S + (size_t)r0 * HID + lk;
        gaX[it] = XB + (size_t)r0 * IN_DIM + lk;
        gb[it]  = B + (size_t)(n0 + rr + lrow8) * KTOT + lk;
    }

    for (int ki = 0; ki < KTOT / TK; ++ki) {
        const bool fromS = (ki * TK < HID);
#pragma unroll
        for (int it = 0; it < 4; ++it) {
            const int rr = (wave * 4 + it) * 8;
            const short* a0 = fromS ? gaS[it] : gaX[it];
            __builtin_amdgcn_global_load_lds(
                (const __attribute__((address_space(1))) void*)a0,
                (__attribute__((address_space(3))) void*)(As + rr * TK), 16, 0, 0);
            __builtin_amdgcn_global_load_lds(
                (const __attribute__((address_space(1))) void*)gb[it],
                (__attribute__((address_space(3))) void*)(Bs + rr * TK), 16, 0, 0);
            gaS[it] += TK; gb[it] += TK;
        }
        __syncthreads();
#pragma unroll
        for (int c2 = 0; c2 < 2; ++c2) {
            short8 af[4], bf[4];
#pragma unroll
            for (int i = 0; i < 4; ++i) {
                af[i] = *(const short8*)(As + aoff[i][c2]);
                bf[i] = *(const short8*)(Bs + boff[i][c2]);
            }
#pragma unroll
            for (int i = 0; i < 4; ++i)
#pragma unroll
                for (int j = 0; j < 4; ++j)
                    acc[i][j] = __builtin_amdgcn_mfma_f32_16x16x32_bf16(af[i], bf[j], acc[i][j], 0, 0, 0);
        }
        __syncthreads();
    }

    gates_epilogue(acc, m0, bx, wave, lane, 0, bias_g, cell, Sout, ridx, n_act);
    __syncthreads();   // protect As/Bs before caller's next tile
}

// R21 midfin: TMF=16 (2 blocks/CU TLP) + 2-phase double-buffer + halt-dot
// fused into the GEMM (R20/R21-verified: absmax bit-identical, total
// 437->404). Wave w owns cols w*32..+31; all waves share the A fragment.
__device__ __forceinline__ void midfin_tile(
    short* As0, short* As1, short* Bs0, short* Bs1, int tid,
    const short* __restrict__ Snew, const short* __restrict__ P,
    const float* __restrict__ bias_p, const float* __restrict__ W_halt,
    const float* __restrict__ W2, const float* __restrict__ b2,
    float* __restrict__ outp, float* __restrict__ p_sum,
    const int* __restrict__ rprev, int* __restrict__ rnext,
    int* __restrict__ cnt, int t, int m0, int n_act)
{
    const int wave = tid >> 6, lane = tid & 63;
    const int colq = lane & 15, q = lane >> 4;
    const int lrow8 = lane >> 3;
    const int lk    = (((lane & 7) ^ lrow8) * 8);
    const int xq = colq & 7;

    float4v acc[2];
    acc[0] = (float4v)0.f; acc[1] = (float4v)0.f;
    float4v acc_h = (float4v)0.f;

    // per-lane source rows (rows beyond n_act read stale-but-in-range ridx
    // entries -> safe dummy gathers, results masked at finalize)
    const int arow_ = (wave < 2) ? rprev[m0 + wave * 8 + lrow8] : 0;
    const short* ga = Snew + (size_t)arow_ * HID + lk;
    const short* gbp[4];
#pragma unroll
    for (int g = 0; g < 4; ++g)
        gbp[g] = P + (size_t)(wave * 32 + g * 8 + lrow8) * HID + lk;
    const short* gbh[2];
#pragma unroll
    for (int l = 0; l < 2; ++l)
        gbh[l] = P + (size_t)(128 + l * 8 + lrow8) * HID + lk;

    auto stage = [&](int ks, short* Asb, short* Bsb) {
        const int k0 = ks * TK;
        if (wave < 2)   // wave-uniform: A rows wave*8..+7
            __builtin_amdgcn_global_load_lds(
                (const __attribute__((address_space(1))) void*)(ga + k0),
                (__attribute__((address_space(3))) void*)(Asb + (wave * 8) * TK), 16, 0, 0);
#pragma unroll
        for (int g = 0; g < 4; ++g)
            __builtin_amdgcn_global_load_lds(
                (const __attribute__((address_space(1))) void*)(gbp[g] + k0),
                (__attribute__((address_space(3))) void*)(Bsb + (wave * 32 + g * 8) * TK), 16, 0, 0);
        if (wave == 3)  // wave-uniform: halt rows 128..143
#pragma unroll
            for (int l = 0; l < 2; ++l)
                __builtin_amdgcn_global_load_lds(
                    (const __attribute__((address_space(1))) void*)(gbh[l] + k0),
                    (__attribute__((address_space(3))) void*)(Bsb + (128 + l * 8) * TK), 16, 0, 0);
    };

    stage(0, As0, Bs0);
    __syncthreads();   // drains prologue stage

    for (int ks = 0; ks < HID / TK; ++ks) {
        const int cur = ks & 1;
        if (ks + 1 < HID / TK)   // issue next stage BEFORE compute
            stage(ks + 1, cur ? As0 : As1, cur ? Bs0 : Bs1);
        const short* Asb = cur ? As1 : As0;
        const short* Bsb = cur ? Bs1 : Bs0;
#pragma unroll
        for (int c2 = 0; c2 < 2; ++c2) {
            const int xt = ((q + 4 * c2) ^ xq) << 3;
            const short8 af = *(const short8*)(Asb + colq * TK + xt);
            const short8 bf0 = *(const short8*)(Bsb + (wave * 32 + colq) * TK + xt);
            const short8 bf1 = *(const short8*)(Bsb + (wave * 32 + 16 + colq) * TK + xt);
            acc[0] = __builtin_amdgcn_mfma_f32_16x16x32_bf16(af, bf0, acc[0], 0, 0, 0);
            acc[1] = __builtin_amdgcn_mfma_f32_16x16x32_bf16(af, bf1, acc[1], 0, 0, 0);
            if (wave == 0) {   // halt fragment: B rows 128..143
                const short8 bh = *(const short8*)(Bsb + (128 + colq) * TK + xt);
                acc_h = __builtin_amdgcn_mfma_f32_16x16x32_bf16(af, bh, acc_h, 0, 0, 0);
            }
        }
        __syncthreads();   // reads retired (lgkm) + next stage landed (vmcnt)
    }

    // aliases over As0 (k-loop done; last barrier above protects)
    float* red  = (float*)As0;          // 64 floats: [w][q][r]
    float* hbuf = ((float*)As0) + 64;   // 16 floats

    // halt values: wave 0's col-0 lanes hold state.W_halt for row q*4+r
    if (wave == 0 && colq == 0) {
#pragma unroll
        for (int r = 0; r < 4; ++r)
            hbuf[q * 4 + r] = acc_h[r];
    }

    // relu + W2-dot over this wave's 32 cols, reduce over colq
    float pr[4];
#pragma unroll
    for (int r = 0; r < 4; ++r) pr[r] = 0.f;
#pragma unroll
    for (int nj = 0; nj < 2; ++nj) {
        const int col = wave * 32 + nj * 16 + colq;
        const float b = bias_p[col];
        const float w2 = W2[col];
#pragma unroll
        for (int r = 0; r < 4; ++r)
            pr[r] += fmaxf(acc[nj][r] + b, 0.f) * w2;
    }
#pragma unroll
    for (int r = 0; r < 4; ++r) {
        float v = pr[r];
        v += __shfl_down(v, 8, 16);
        v += __shfl_down(v, 4, 16);
        v += __shfl_down(v, 2, 16);
        v += __shfl_down(v, 1, 16);
        if (colq == 0)
            red[(wave * 4 + q) * 4 + r] = v;
    }
    __syncthreads();

    // finalize: one thread per row (16 rows)
    if (tid < TMF) {
        const int pos = m0 + tid;
        if (pos < n_act) {
            const int lq = tid >> 2, r = tid & 3;
            float odot = 0.f;
#pragma unroll
            for (int w = 0; w < 4; ++w)
                odot += red[(w * 4 + lq) * 4 + r];
            const int row = rprev[pos];
            const float ov = sigmoidf_(odot + b2[0]);
            const float h  = sigmoidf_(hbuf[tid] + bias_p[OMID]);
            const float ps = p_sum[row];
            const float pn = ps + h;
            const bool fin = (pn >= 1.f - 1e-3f) || (t == MAX_ITER - 1);
            const float halt = fin ? (1.f - ps) : h;
            outp[row] += ov * halt;
            p_sum[row] = fin ? 1.f : pn;
            if (!fin) {
                const int d = atomicAdd(&cnt[t + 1], 1);
                astore(&rnext[d], row);
            }
        }
    }
    __syncthreads();   // protect As/Bs aliases before caller reuses LDS
}

// Standalone midfin dispatch (steps 0..2): 512 blocks x 16-row tiles.
__global__ __launch_bounds__(256) void midfin_k(
    const short* __restrict__ Snew, const short* __restrict__ P,
    const float* __restrict__ bias_p, const float* __restrict__ W_halt,
    const float* __restrict__ W2, const float* __restrict__ b2,
    float* __restrict__ outp, float* __restrict__ p_sum,
    const int* __restrict__ rprev, int* __restrict__ rnext,
    int* __restrict__ cnt, int t)
{
    __shared__ short As[2][TMF * TK];   // 2 x 2 KiB
    __shared__ short Bs[2][NBH * TK];   // 2 x 18 KiB
    const int n_act = cnt[t];
    for (int tile = blockIdx.x; tile * TMF < n_act; tile += gridDim.x)
        midfin_tile(As[0], As[1], Bs[0], Bs[1], threadIdx.x,
                    Snew, P, bias_p, W_halt, W2, b2,
                    outp, p_sum, rprev, rnext, cnt, t, tile * TMF, n_act);
}

// Persistent 64-block tail: steps 3..7 (midfin+gates) with in-kernel
// barriers. For this data cnt[3]==0 so it exits after one gbar; full loop
// retained for arbitrary data.
__global__ __launch_bounds__(256) void tail_k(
    const short* __restrict__ Wg, const float* __restrict__ bias_g,
    const short* __restrict__ P, const float* __restrict__ bias_p,
    const float* __restrict__ W_halt, const float* __restrict__ W2,
    const float* __restrict__ b2,
    short* __restrict__ S0, short* __restrict__ S1,
    const short* __restrict__ XB,
    float* __restrict__ cell, float* __restrict__ outp,
    float* __restrict__ p_sum,
    int* __restrict__ ridx0, int* __restrict__ ridx1,
    int* __restrict__ cnt, int* __restrict__ bar)
{
    __shared__ short As[2][TM * TK];    // gates_tile uses As[0]/Bs[0] flat
    __shared__ short Bs[2][NBH * TK];   // (NBH*TK = 9216 >= TN*TK = 8192)
    const int tid = threadIdx.x;
    int phase = 0;
    int t = 3;
    while (true) {
        short* Snew = (t & 1) ? S0 : S1;        // state written by gates(t)
        const int* rprev = (t & 1) ? ridx1 : ridx0;  // L_t
        int* rnext = (t & 1) ? ridx0 : ridx1;        // L_{t+1}
        const int n = aload(&cnt[t]);
        for (int tile = blockIdx.x; tile * TMF < n; tile += gridDim.x)
            midfin_tile(As[0], As[1], Bs[0], Bs[1], tid,
                        Snew, P, bias_p, W_halt, W2, b2,
                        outp, p_sum, rprev, rnext, cnt, t, tile * TMF, n);
        if (t == MAX_ITER - 1) break;
        ++phase; gbar(bar, phase, tid);          // publish cnt[t+1], ridx, p_sum
        const int n1 = aload(&cnt[t + 1]);
        if (n1 == 0) break;                      // uniform across blocks
        {
            short* Sot = (t & 1) ? S1 : S0;
            const int ntiles = ((n1 + TM - 1) / TM) * (NGATES / TN);
            for (int e = blockIdx.x; e < ntiles; e += gridDim.x)
                gates_tile(As[0], Bs[0], tid, Snew, XB, Wg, bias_g, cell, Sot,
                           rnext, n1, (e >> 5) * TM, e & 31);
        }
        ++phase; gbar(bar, phase, tid);          // publish Sout, cell
        ++t;
    }
}

// R19 setup: x4 VECTORIZED weight packing (float4 in, short4 out).
// NOTE: S0/S1/cell are deliberately NOT initialized — at t=0 all rows are
// active, so gates(0) writes every state/cell entry before any read.
#define SETUP_XB4   (BATCH * IN_DIM / 4)
#define SETUP_WG4   (NGATES * (KTOT / 4))
#define SETUP_P4    (NP * (HID / 4))
#define SETUP_TOT4  (SETUP_XB4 + SETUP_WG4 + SETUP_P4)
__global__ __launch_bounds__(256) void setup_k(
    const float* __restrict__ x,
    const float* __restrict__ Whi, const float* __restrict__ Whf,
    const float* __restrict__ Whc, const float* __restrict__ Who,
    const float* __restrict__ Wxi, const float* __restrict__ Wxf,
    const float* __restrict__ Wxc, const float* __restrict__ Wxo,
    const float* __restrict__ bxi, const float* __restrict__ bhi,
    const float* __restrict__ bxf, const float* __restrict__ bhf,
    const float* __restrict__ bxc, const float* __restrict__ bhc,
    const float* __restrict__ bxo, const float* __restrict__ bho,
    const float* __restrict__ W1, const float* __restrict__ b1,
    const float* __restrict__ W_halt, const float* __restrict__ b_halt,
    short* __restrict__ XB,
    float* __restrict__ p_sum,
    int* __restrict__ ridx0, int* __restrict__ ridx1, int* __restrict__ cnt,
    int* __restrict__ bar, float* __restrict__ outp,
    short* __restrict__ Wg, float* __restrict__ bias_g,
    short* __restrict__ P, float* __restrict__ bias_p)
{
    int idx = blockIdx.x * 256 + threadIdx.x;
    if (idx < SETUP_XB4) {
        const int row = idx >> 4, k4 = (idx & 15) * 4;
        const float4f v = *(const float4f*)(x + row * IN_DIM + k4);
        short4v o;
#pragma unroll
        for (int e = 0; e < 4; ++e) o[e] = f2bf(v[e]);
        *(short4v*)(XB + row * IN_DIM + k4) = o;
        if (k4 == 0) {
            p_sum[row] = 0.f;
            outp[row] = 0.f;
            ridx0[row] = row;   // step 0: identity compaction
            ridx1[row] = 0;     // in-range dummies for padded tile reads
        }
        if (idx == 0) {
            for (int k = 0; k <= MAX_ITER; ++k) cnt[k] = (k == 0) ? BATCH : 0;
            bar[0] = 0;
        }
        return;
    }
    idx -= SETUP_XB4;
    if (idx < SETUP_WG4) {
        const int n = idx / (KTOT / 4), k4 = (idx - n * (KTOT / 4)) * 4;
        // interleaved layout: n = 64*G + 16*g + q  ->  gate g of hidden h=16*G+q
        const int G = n >> 6, g = (n >> 4) & 3, qq = n & 15;
        const int h = G * 16 + qq;
        const float* Wh = (g == 0) ? Whi : (g == 1) ? Whf : (g == 2) ? Whc : Who;
        const float* Wx = (g == 0) ? Wxi : (g == 1) ? Wxf : (g == 2) ? Wxc : Wxo;
        const float4f v = (k4 < HID)
            ? *(const float4f*)(Wh + h * HID + k4)
            : *(const float4f*)(Wx + h * IN_DIM + (k4 - HID));
        short4v o;
#pragma unroll
        for (int e = 0; e < 4; ++e) o[e] = f2bf(v[e]);
        *(short4v*)(Wg + (size_t)n * KTOT + k4) = o;
        if (k4 == 0) {
            const float* bx = (g == 0) ? bxi : (g == 1) ? bxf : (g == 2) ? bxc : bxo;
            const float* bh = (g == 0) ? bhi : (g == 1) ? bhf : (g == 2) ? bhc : bho;
            bias_g[n] = bx[h] + bh[h];
        }
        return;
    }
    idx -= SETUP_WG4;
    if (idx < SETUP_P4) {
        const int n = idx >> 8, k4 = (idx & 255) * 4;
        float4f v;
        if (n < OMID)      v = *(const float4f*)(W1 + n * HID + k4);
        else if (n == OMID) v = *(const float4f*)(W_halt + k4);
        else { v[0] = 0.f; v[1] = 0.f; v[2] = 0.f; v[3] = 0.f; }
        short4v o;
#pragma unroll
        for (int e = 0; e < 4; ++e) o[e] = f2bf(v[e]);
        *(short4v*)(P + (size_t)n * HID + k4) = o;
        if (k4 == 0) bias_p[n] = (n < OMID) ? b1[n] : (n == OMID ? b_halt[0] : 0.f);
    }
}

extern "C" void kernel_launch(void* const* d_in, const int* in_sizes, int n_in,
                              void* d_out, int out_size, void* d_ws, size_t ws_size,
                              hipStream_t stream) {
    const float* x    = (const float*)d_in[0];
    const float* Wxi  = (const float*)d_in[1];
    const float* bxi  = (const float*)d_in[2];
    const float* Whi  = (const float*)d_in[3];
    const float* bhi  = (const float*)d_in[4];
    const float* Wxf  = (const float*)d_in[5];
    const float* bxf  = (const float*)d_in[6];
    const float* Whf  = (const float*)d_in[7];
    const float* bhf  = (const float*)d_in[8];
    const float* Wxc  = (const float*)d_in[9];
    const float* bxc  = (const float*)d_in[10];
    const float* Whc  = (const float*)d_in[11];
    const float* bhc  = (const float*)d_in[12];
    const float* Wxo  = (const float*)d_in[13];
    const float* bxo  = (const float*)d_in[14];
    const float* Who  = (const float*)d_in[15];
    const float* bho  = (const float*)d_in[16];
    const float* W_halt = (const float*)d_in[17];
    const float* b_halt = (const float*)d_in[18];
    const float* W1   = (const float*)d_in[19];
    const float* b1   = (const float*)d_in[20];
    const float* W2   = (const float*)d_in[21];
    const float* b2   = (const float*)d_in[22];

    char* p = (char*)d_ws;
    auto carve = [&](size_t bytes) { char* r = p; p += (bytes + 255) & ~(size_t)255; return r; };
    short* S0     = (short*)carve((size_t)BATCH * HID * 2);
    short* S1     = (short*)carve((size_t)BATCH * HID * 2);
    short* XB     = (short*)carve((size_t)BATCH * IN_DIM * 2);
    short* Wg     = (short*)carve((size_t)NGATES * KTOT * 2);
    float* bias_g = (float*)carve((size_t)NGATES * 4);
    short* P      = (short*)carve((size_t)NP * HID * 2);
    float* bias_p = (float*)carve((size_t)NP * 4);
    float* cell   = (float*)carve((size_t)BATCH * HID * 4);
    float* p_sum  = (float*)carve((size_t)BATCH * 4);
    int*   ridx0  = (int*)carve((size_t)BATCH * 4);
    int*   ridx1  = (int*)carve((size_t)BATCH * 4);
    int*   cnt    = (int*)carve((size_t)(MAX_ITER + 1) * 4);
    int*   bar    = (int*)carve(256);
    float* outp   = (float*)d_out;

    setup_k<<<(SETUP_TOT4 + 255) / 256, 256, 0, stream>>>(
        x, Whi, Whf, Whc, Who, Wxi, Wxf, Wxc, Wxo,
        bxi, bhi, bxf, bhf, bxc, bhc, bxo, bho,
        W1, b1, W_halt, b_halt,
        XB, p_sum, ridx0, ridx1, cnt, bar, outp,
        Wg, bias_g, P, bias_p);

    // t=0: state==0 -> x-part only (1 k-iter from XB), cell write-only
    gates_k<<<dim3(32, 64), 256, 0, stream>>>(
        S0, XB, Wg + HID, bias_g, 1, 0, 1, cell, S1, ridx0, cnt, 0);
    midfin_k<<<512, 256, 0, stream>>>(
        S1, P, bias_p, W_halt, W2, b2, outp, p_sum, ridx0, ridx1, cnt, 0);
    // t=1: full batch (64 m-tiles -> 1 per y-block)
    gates_k<<<dim3(32, 64), 256, 0, stream>>>(
        S1, XB, Wg, bias_g, KTOT / TK, HID, 0, cell, S0, ridx1, cnt, 1);
    midfin_k<<<512, 256, 0, stream>>>(
        S0, P, bias_p, W_halt, W2, b2, outp, p_sum, ridx1, ridx0, cnt, 1);
    // t=2: ~half batch (~32 m-tiles; surplus y-blocks exit immediately)
    gates_k<<<dim3(32, 64), 256, 0, stream>>>(
        S0, XB, Wg, bias_g, KTOT / TK, HID, 0, cell, S1, ridx0, cnt, 2);
    midfin_k<<<512, 256, 0, stream>>>(
        S1, P, bias_p, W_halt, W2, b2, outp, p_sum, ridx0, ridx1, cnt, 2);
    // steps 3..7 (empty for this data) in one persistent 64-block kernel
    tail_k<<<TAILB, 256, 0, stream>>>(
        Wg, bias_g, P, bias_p, W_halt, W2, b2,
        S0, S1, XB, cell, outp, p_sum, ridx0, ridx1, cnt, bar);
}

// Round 11
// 406.087 us; speedup vs baseline: 1.1439x; 1.1439x over previous
//
#include <hip/hip_runtime.h>
#include <hip/hip_bf16.h>

#define BATCH 8192
#define IN_DIM 64
#define HID 1024
#define KTOT 1088   // HID + IN_DIM (fused K; weights laid out [n][KTOT])
#define NGATES 4096 // 4*HID, column c = 64*G + 16*g + q -> gate g of h=16*G+q
#define OMID 128
#define NP 256      // packed P rows (W1 0..127, W_halt 128, zeros)
#define MAX_ITER 8

#define TM 128
#define TN 128
#define TK 64
#define TMF 16      // midfin m-tile (R21: 16 rows -> 512 tiles = 2 blocks/CU)
#define NBH 144     // midfin Bs rows: 128 W1 + 16 (W_halt @128 + zeros)
#define GTM 256     // gates_k m-tile
#define GTN 256     // gates_k n-tile
#define TAILB 64    // tail_k blocks: few enough that a device barrier is cheap

typedef __attribute__((ext_vector_type(8))) short short8;
typedef __attribute__((ext_vector_type(4))) float float4v;
typedef __attribute__((ext_vector_type(4))) float float4f;
typedef __attribute__((ext_vector_type(4))) short short4v;

__device__ __forceinline__ float bf2f(short s) {
    union { float f; unsigned u; } v; v.u = ((unsigned)(unsigned short)s) << 16; return v.f;
}
__device__ __forceinline__ short f2bf(float f) {
    union { float f; unsigned u; } v; v.f = f;
    unsigned r = v.u + 0x7fff + ((v.u >> 16) & 1);  // round-to-nearest-even
    return (short)(r >> 16);
}
__device__ __forceinline__ float sigmoidf_(float x) {
    float xc = fminf(fmaxf(x, -30.f), 30.f);
    return 1.f / (1.f + __expf(-xc));
}
__device__ __forceinline__ float tanhf_(float x) {
    float xc = fminf(fmaxf(x, -15.f), 15.f);
    float e = __expf(2.f * xc);
    return (e - 1.f) / (e + 1.f);
}
__device__ __forceinline__ int aload(const int* p) {
    return __hip_atomic_load((int*)p, __ATOMIC_RELAXED, __HIP_MEMORY_SCOPE_AGENT);
}
__device__ __forceinline__ void astore(int* p, int v) {
    __hip_atomic_store(p, v, __ATOMIC_RELAXED, __HIP_MEMORY_SCOPE_AGENT);
}

// 64-block generation barrier (R8-verified; R5/R7/R11: ANY wider barrier
// pays 50-100us in cross-XCD L2 invalidate traffic). RELAXED polling by one
// lane per block with s_sleep; fences only at the crossing points.
__device__ __forceinline__ void gbar(int* bar, int phase, int tid) {
    __syncthreads();
    if (tid == 0) {
        __threadfence();
        __hip_atomic_fetch_add(bar, 1, __ATOMIC_ACQ_REL, __HIP_MEMORY_SCOPE_AGENT);
        while (aload(bar) < TAILB * phase)
            __builtin_amdgcn_s_sleep(8);
        __threadfence();
    }
    __syncthreads();
}

// Shared epilogue: fused LSTM cell update for one 128-row m-tile's
// accumulators (used by the 128^2 gates_tile inside tail_k).
// first=1 (t==0): cell is write-only (c = i*cg == f*0 + i*cg bit-exactly),
// so cell never needs zero-init and t=0 skips the 33.6MB cell read.
__device__ __forceinline__ void gates_epilogue(
    const float4v (&acc)[4][4], int m0, int bx, int wave, int lane, int first,
    const float* __restrict__ bias_g, float* __restrict__ cell,
    short* __restrict__ Sout, const int* __restrict__ ridx, int n_act)
{
    const int wm = wave & 1, wn = wave >> 1;
    const int colq = lane & 15, q = lane >> 4;
    const int G = bx * 2 + wn;   // 64-col group = 16 hidden units
    const int h = G * 16 + colq;
    const float bi  = bias_g[G * 64 +  0 + colq];
    const float bff = bias_g[G * 64 + 16 + colq];
    const float bc  = bias_g[G * 64 + 32 + colq];
    const float bo  = bias_g[G * 64 + 48 + colq];
#pragma unroll
    for (int i = 0; i < 4; ++i) {
        const int pbase = m0 + wm * 64 + i * 16 + q * 4;
#pragma unroll
        for (int r = 0; r < 4; ++r) {
            const int pos = pbase + r;
            if (pos < n_act) {
                const int row = ridx[pos];
                const float ig = sigmoidf_(acc[i][0][r] + bi);
                const float fg = sigmoidf_(acc[i][1][r] + bff);
                const float cg = tanhf_(acc[i][2][r] + bc);
                const float og = sigmoidf_(acc[i][3][r] + bo);
                const size_t ci = (size_t)row * HID + h;
                const float c = first ? (ig * cg) : (fg * cell[ci] + ig * cg);
                cell[ci] = c;
                Sout[(size_t)row * HID + h] = f2bf(og * tanhf_(c));
            }
        }
    }
}

// Gates GEMM, R23 = R21 revert (best measured: total 404.5us, this kernel
// 116.5us). Closed experiments: (a) schedules — 2-block lockstep 127,
// 2-phase dbuf 116.5, zero-wait async 121.9, 4-phase 122.5, 4-phase
// double-fenced 120.5: all 575-627 TF; (b) occupancy/operand-path (R22) —
// 128^2 4-wave + B-from-global: occupancy 21->31% as predicted but 184us
// (FETCH +30MB: B panels not L2-resident under multi-block contention;
// B-loads coupled to MFMA consumption = exposed L2 latency). LDS staging
// + the R14 2-phase body is the verified fixed point.
// XCD-rectangle swizzle kept (FETCH 95->69 MB verified, time-neutral).
__global__ __launch_bounds__(512, 1) void gates_k(
    const short* __restrict__ S, const short* __restrict__ XB,
    const short* __restrict__ B,
    const float* __restrict__ bias_g, int nK, int hidK, int first,
    float* __restrict__ cell, short* __restrict__ Sout,
    const int* __restrict__ ridx, const int* __restrict__ cnt, int t)
{
    __shared__ short As[2][GTM * TK];   // 2 x 32 KiB
    __shared__ short Bs[2][GTN * TK];   // 2 x 32 KiB
    const int n_act = cnt[t];
    const int tid  = threadIdx.x;
    const int wave = tid >> 6, lane = tid & 63;
    const int wm2 = wave >> 2, wn4 = wave & 3;   // wave -> 128-row half x 64-col quarter
    const int colq = lane & 15, q = lane >> 4;
    const int lrow8 = lane >> 3;
    const int lk    = (((lane & 7) ^ lrow8) * 8);   // pre-swizzled source offset
    const int xq = colq & 7;
    const int abase = (wm2 * 128 + colq) * TK;   // shorts
    const int bbase = (wn4 * 64  + colq) * TK;   // shorts

    // XCD-rectangle swizzle (grid is 16x16 for all gates_k launches).
    int bx, byS;
    {
        const int lin  = (int)blockIdx.x + 16 * (int)blockIdx.y;  // hw order
        const int xcd  = lin & 7;          // round-robin XCD assignment
        const int slot = lin >> 3;         // 0..31 within this XCD
        bx  = (xcd & 1) * 8 + (slot & 7);  // 8 consecutive x per XCD
        byS = (xcd >> 1) * 4 + (slot >> 3);// 4 consecutive y per XCD
    }
    const int n0 = bx * GTN;

    for (int by = byS; by * GTM < n_act; by += 16) {
        const int m0 = by * GTM;

        // per-wave staged rows: wave*32 + it*8 + lrow8 (A and B share the map)
        int rows_[4];
        const short* gb[4];
#pragma unroll
        for (int it = 0; it < 4; ++it) {
            const int rr = wave * 32 + it * 8 + lrow8;
            rows_[it] = ridx[m0 + rr];
            gb[it] = B + (size_t)(n0 + rr) * KTOT + lk;
        }

        float4v acc[8][4];
#pragma unroll
        for (int i = 0; i < 8; ++i)
#pragma unroll
            for (int j = 0; j < 4; ++j) acc[i][j] = (float4v)0.f;

        auto stage = [&](int ki, int buf) {
            const int kk = ki * TK;
            const bool fromS = (kk < hidK);   // kernel-uniform branch
#pragma unroll
            for (int it = 0; it < 4; ++it) {
                const int dst = (wave * 32 + it * 8) * TK;
                const short* sa = fromS
                    ? (S  + (size_t)rows_[it] * HID    + kk + lk)
                    : (XB + (size_t)rows_[it] * IN_DIM + lk);
                __builtin_amdgcn_global_load_lds(
                    (const __attribute__((address_space(1))) void*)sa,
                    (__attribute__((address_space(3))) void*)(As[buf] + dst), 16, 0, 0);
                __builtin_amdgcn_global_load_lds(
                    (const __attribute__((address_space(1))) void*)(gb[it] + kk),
                    (__attribute__((address_space(3))) void*)(Bs[buf] + dst), 16, 0, 0);
            }
        };

        stage(0, 0);
        __syncthreads();   // drains prologue stage

        for (int ki = 0; ki < nK; ++ki) {
            const int cur = ki & 1;
            if (ki + 1 < nK) stage(ki + 1, cur ^ 1);   // issue BEFORE compute
            const short* Ac = As[cur];
            const short* Bc = Bs[cur];
#pragma unroll
            for (int c2 = 0; c2 < 2; ++c2) {
                const int xt = ((q + 4 * c2) ^ xq) << 3;
                short8 af[8], bf[4];
#pragma unroll
                for (int i = 0; i < 8; ++i)
                    af[i] = *(const short8*)(Ac + abase + i * (16 * TK) + xt);
#pragma unroll
                for (int j = 0; j < 4; ++j)
                    bf[j] = *(const short8*)(Bc + bbase + j * (16 * TK) + xt);
#pragma unroll
                for (int i = 0; i < 8; ++i)
#pragma unroll
                    for (int j = 0; j < 4; ++j)
                        acc[i][j] = __builtin_amdgcn_mfma_f32_16x16x32_bf16(af[i], bf[j], acc[i][j], 0, 0, 0);
            }
            // one barrier per K-step: lgkm (ds_reads) drained by MFMA deps,
            // vmcnt drained inside __syncthreads -> buf[cur^1] ready.
            __syncthreads();
        }

        // epilogue: per wave, cols n0 + wn4*64 .. +63 = one 64-col G-group
        // = all 4 gates of 16 hidden units (interleaved weight layout).
        const int G = bx * 4 + wn4;
        const int h = G * 16 + colq;
        const float bi  = bias_g[G * 64 +  0 + colq];
        const float bff = bias_g[G * 64 + 16 + colq];
        const float bc  = bias_g[G * 64 + 32 + colq];
        const float bo  = bias_g[G * 64 + 48 + colq];
#pragma unroll
        for (int i = 0; i < 8; ++i) {
            const int pbase = m0 + wm2 * 128 + i * 16 + q * 4;
#pragma unroll
            for (int r = 0; r < 4; ++r) {
                const int pos = pbase + r;
                if (pos < n_act) {
                    const int row = ridx[pos];
                    const float ig = sigmoidf_(acc[i][0][r] + bi);
                    const float fg = sigmoidf_(acc[i][1][r] + bff);
                    const float cg = tanhf_(acc[i][2][r] + bc);
                    const float og = sigmoidf_(acc[i][3][r] + bo);
                    const size_t ci = (size_t)row * HID + h;
                    const float c = first ? (ig * cg) : (fg * cell[ci] + ig * cg);
                    cell[ci] = c;
                    Sout[(size_t)row * HID + h] = f2bf(og * tanhf_(c));
                }
            }
        }
        // last K-iter ended in __syncthreads; epilogue touches no LDS;
        // next m-tile's stage(0,0) is followed by its own __syncthreads.
    }
}

// Single-m-tile gates (R10 form, split-A, 128^2) — used only inside tail_k.
__device__ __forceinline__ void gates_tile(
    short* As, short* Bs, int tid,
    const short* __restrict__ S, const short* __restrict__ XB,
    const short* __restrict__ B,
    const float* __restrict__ bias_g,
    float* __restrict__ cell, short* __restrict__ Sout,
    const int* __restrict__ ridx, int n_act, int m0, int bx)
{
    const int wave = tid >> 6, lane = tid & 63;
    const int wm = wave & 1, wn = wave >> 1;
    const int colq = lane & 15, q = lane >> 4;
    const int lrow8 = lane >> 3;
    const int lk    = (((lane & 7) ^ lrow8) * 8);
    const int n0 = bx * TN;

    int aoff[4][2], boff[4][2];
#pragma unroll
    for (int i = 0; i < 4; ++i) {
        const int Ra = wm * 64 + i * 16 + colq;
        const int Rb = wn * 64 + i * 16 + colq;
#pragma unroll
        for (int c2 = 0; c2 < 2; ++c2) {
            const int C = q + 4 * c2;
            aoff[i][c2] = Ra * TK + ((C ^ (Ra & 7)) << 3);
            boff[i][c2] = Rb * TK + ((C ^ (Rb & 7)) << 3);
        }
    }

    float4v acc[4][4];
#pragma unroll
    for (int i = 0; i < 4; ++i)
#pragma unroll
        for (int j = 0; j < 4; ++j) acc[i][j] = (float4v)0.f;

    const short* gaS[4];
    const short* gaX[4];
    const short* gb[4];
#pragma unroll
    for (int it = 0; it < 4; ++it) {
        const int rr = (wave * 4 + it) * 8;
        const int r0 = ridx[m0 + rr + lrow8];
        gaS[it] = S + (size_t)r0 * HID + lk;
        gaX[it] = XB + (size_t)r0 * IN_DIM + lk;
        gb[it]  = B + (size_t)(n0 + rr + lrow8) * KTOT + lk;
    }

    for (int ki = 0; ki < KTOT / TK; ++ki) {
        const bool fromS = (ki * TK < HID);
#pragma unroll
        for (int it = 0; it < 4; ++it) {
            const int rr = (wave * 4 + it) * 8;
            const short* a0 = fromS ? gaS[it] : gaX[it];
            __builtin_amdgcn_global_load_lds(
                (const __attribute__((address_space(1))) void*)a0,
                (__attribute__((address_space(3))) void*)(As + rr * TK), 16, 0, 0);
            __builtin_amdgcn_global_load_lds(
                (const __attribute__((address_space(1))) void*)gb[it],
                (__attribute__((address_space(3))) void*)(Bs + rr * TK), 16, 0, 0);
            gaS[it] += TK; gb[it] += TK;
        }
        __syncthreads();
#pragma unroll
        for (int c2 = 0; c2 < 2; ++c2) {
            short8 af[4], bf[4];
#pragma unroll
            for (int i = 0; i < 4; ++i) {
                af[i] = *(const short8*)(As + aoff[i][c2]);
                bf[i] = *(const short8*)(Bs + boff[i][c2]);
            }
#pragma unroll
            for (int i = 0; i < 4; ++i)
#pragma unroll
                for (int j = 0; j < 4; ++j)
                    acc[i][j] = __builtin_amdgcn_mfma_f32_16x16x32_bf16(af[i], bf[j], acc[i][j], 0, 0, 0);
        }
        __syncthreads();
    }

    gates_epilogue(acc, m0, bx, wave, lane, 0, bias_g, cell, Sout, ridx, n_act);
    __syncthreads();   // protect As/Bs before caller's next tile
}

// R21 midfin: TMF=16 (2 blocks/CU TLP) + 2-phase double-buffer + halt-dot
// fused into the GEMM (R20/R21-verified: absmax bit-identical, total
// 437->404). Wave w owns cols w*32..+31; all waves share the A fragment.
__device__ __forceinline__ void midfin_tile(
    short* As0, short* As1, short* Bs0, short* Bs1, int tid,
    const short* __restrict__ Snew, const short* __restrict__ P,
    const float* __restrict__ bias_p, const float* __restrict__ W_halt,
    const float* __restrict__ W2, const float* __restrict__ b2,
    float* __restrict__ outp, float* __restrict__ p_sum,
    const int* __restrict__ rprev, int* __restrict__ rnext,
    int* __restrict__ cnt, int t, int m0, int n_act)
{
    const int wave = tid >> 6, lane = tid & 63;
    const int colq = lane & 15, q = lane >> 4;
    const int lrow8 = lane >> 3;
    const int lk    = (((lane & 7) ^ lrow8) * 8);
    const int xq = colq & 7;

    float4v acc[2];
    acc[0] = (float4v)0.f; acc[1] = (float4v)0.f;
    float4v acc_h = (float4v)0.f;

    // per-lane source rows (rows beyond n_act read stale-but-in-range ridx
    // entries -> safe dummy gathers, results masked at finalize)
    const int arow_ = (wave < 2) ? rprev[m0 + wave * 8 + lrow8] : 0;
    const short* ga = Snew + (size_t)arow_ * HID + lk;
    const short* gbp[4];
#pragma unroll
    for (int g = 0; g < 4; ++g)
        gbp[g] = P + (size_t)(wave * 32 + g * 8 + lrow8) * HID + lk;
    const short* gbh[2];
#pragma unroll
    for (int l = 0; l < 2; ++l)
        gbh[l] = P + (size_t)(128 + l * 8 + lrow8) * HID + lk;

    auto stage = [&](int ks, short* Asb, short* Bsb) {
        const int k0 = ks * TK;
        if (wave < 2)   // wave-uniform: A rows wave*8..+7
            __builtin_amdgcn_global_load_lds(
                (const __attribute__((address_space(1))) void*)(ga + k0),
                (__attribute__((address_space(3))) void*)(Asb + (wave * 8) * TK), 16, 0, 0);
#pragma unroll
        for (int g = 0; g < 4; ++g)
            __builtin_amdgcn_global_load_lds(
                (const __attribute__((address_space(1))) void*)(gbp[g] + k0),
                (__attribute__((address_space(3))) void*)(Bsb + (wave * 32 + g * 8) * TK), 16, 0, 0);
        if (wave == 3)  // wave-uniform: halt rows 128..143
#pragma unroll
            for (int l = 0; l < 2; ++l)
                __builtin_amdgcn_global_load_lds(
                    (const __attribute__((address_space(1))) void*)(gbh[l] + k0),
                    (__attribute__((address_space(3))) void*)(Bsb + (128 + l * 8) * TK), 16, 0, 0);
    };

    stage(0, As0, Bs0);
    __syncthreads();   // drains prologue stage

    for (int ks = 0; ks < HID / TK; ++ks) {
        const int cur = ks & 1;
        if (ks + 1 < HID / TK)   // issue next stage BEFORE compute
            stage(ks + 1, cur ? As0 : As1, cur ? Bs0 : Bs1);
        const short* Asb = cur ? As1 : As0;
        const short* Bsb = cur ? Bs1 : Bs0;
#pragma unroll
        for (int c2 = 0; c2 < 2; ++c2) {
            const int xt = ((q + 4 * c2) ^ xq) << 3;
            const short8 af = *(const short8*)(Asb + colq * TK + xt);
            const short8 bf0 = *(const short8*)(Bsb + (wave * 32 + colq) * TK + xt);
            const short8 bf1 = *(const short8*)(Bsb + (wave * 32 + 16 + colq) * TK + xt);
            acc[0] = __builtin_amdgcn_mfma_f32_16x16x32_bf16(af, bf0, acc[0], 0, 0, 0);
            acc[1] = __builtin_amdgcn_mfma_f32_16x16x32_bf16(af, bf1, acc[1], 0, 0, 0);
            if (wave == 0) {   // halt fragment: B rows 128..143
                const short8 bh = *(const short8*)(Bsb + (128 + colq) * TK + xt);
                acc_h = __builtin_amdgcn_mfma_f32_16x16x32_bf16(af, bh, acc_h, 0, 0, 0);
            }
        }
        __syncthreads();   // reads retired (lgkm) + next stage landed (vmcnt)
    }

    // aliases over As0 (k-loop done; last barrier above protects)
    float* red  = (float*)As0;          // 64 floats: [w][q][r]
    float* hbuf = ((float*)As0) + 64;   // 16 floats

    // halt values: wave 0's col-0 lanes hold state.W_halt for row q*4+r
    if (wave == 0 && colq == 0) {
#pragma unroll
        for (int r = 0; r < 4; ++r)
            hbuf[q * 4 + r] = acc_h[r];
    }

    // relu + W2-dot over this wave's 32 cols, reduce over colq
    float pr[4];
#pragma unroll
    for (int r = 0; r < 4; ++r) pr[r] = 0.f;
#pragma unroll
    for (int nj = 0; nj < 2; ++nj) {
        const int col = wave * 32 + nj * 16 + colq;
        const float b = bias_p[col];
        const float w2 = W2[col];
#pragma unroll
        for (int r = 0; r < 4; ++r)
            pr[r] += fmaxf(acc[nj][r] + b, 0.f) * w2;
    }
#pragma unroll
    for (int r = 0; r < 4; ++r) {
        float v = pr[r];
        v += __shfl_down(v, 8, 16);
        v += __shfl_down(v, 4, 16);
        v += __shfl_down(v, 2, 16);
        v += __shfl_down(v, 1, 16);
        if (colq == 0)
            red[(wave * 4 + q) * 4 + r] = v;
    }
    __syncthreads();

    // finalize: one thread per row (16 rows)
    if (tid < TMF) {
        const int pos = m0 + tid;
        if (pos < n_act) {
            const int lq = tid >> 2, r = tid & 3;
            float odot = 0.f;
#pragma unroll
            for (int w = 0; w < 4; ++w)
                odot += red[(w * 4 + lq) * 4 + r];
            const int row = rprev[pos];
            const float ov = sigmoidf_(odot + b2[0]);
            const float h  = sigmoidf_(hbuf[tid] + bias_p[OMID]);
            const float ps = p_sum[row];
            const float pn = ps + h;
            const bool fin = (pn >= 1.f - 1e-3f) || (t == MAX_ITER - 1);
            const float halt = fin ? (1.f - ps) : h;
            outp[row] += ov * halt;
            p_sum[row] = fin ? 1.f : pn;
            if (!fin) {
                const int d = atomicAdd(&cnt[t + 1], 1);
                astore(&rnext[d], row);
            }
        }
    }
    __syncthreads();   // protect As/Bs aliases before caller reuses LDS
}

// Standalone midfin dispatch (steps 0..2): 512 blocks x 16-row tiles.
__global__ __launch_bounds__(256) void midfin_k(
    const short* __restrict__ Snew, const short* __restrict__ P,
    const float* __restrict__ bias_p, const float* __restrict__ W_halt,
    const float* __restrict__ W2, const float* __restrict__ b2,
    float* __restrict__ outp, float* __restrict__ p_sum,
    const int* __restrict__ rprev, int* __restrict__ rnext,
    int* __restrict__ cnt, int t)
{
    __shared__ short As[2][TMF * TK];   // 2 x 2 KiB
    __shared__ short Bs[2][NBH * TK];   // 2 x 18 KiB
    const int n_act = cnt[t];
    for (int tile = blockIdx.x; tile * TMF < n_act; tile += gridDim.x)
        midfin_tile(As[0], As[1], Bs[0], Bs[1], threadIdx.x,
                    Snew, P, bias_p, W_halt, W2, b2,
                    outp, p_sum, rprev, rnext, cnt, t, tile * TMF, n_act);
}

// Persistent 64-block tail: steps 3..7 (midfin+gates) with in-kernel
// barriers. For this data cnt[3]==0 so it exits after one gbar; full loop
// retained for arbitrary data.
__global__ __launch_bounds__(256) void tail_k(
    const short* __restrict__ Wg, const float* __restrict__ bias_g,
    const short* __restrict__ P, const float* __restrict__ bias_p,
    const float* __restrict__ W_halt, const float* __restrict__ W2,
    const float* __restrict__ b2,
    short* __restrict__ S0, short* __restrict__ S1,
    const short* __restrict__ XB,
    float* __restrict__ cell, float* __restrict__ outp,
    float* __restrict__ p_sum,
    int* __restrict__ ridx0, int* __restrict__ ridx1,
    int* __restrict__ cnt, int* __restrict__ bar)
{
    __shared__ short As[2][TM * TK];    // gates_tile uses As[0]/Bs[0] flat
    __shared__ short Bs[2][NBH * TK];   // (NBH*TK = 9216 >= TN*TK = 8192)
    const int tid = threadIdx.x;
    int phase = 0;
    int t = 3;
    while (true) {
        short* Snew = (t & 1) ? S0 : S1;        // state written by gates(t)
        const int* rprev = (t & 1) ? ridx1 : ridx0;  // L_t
        int* rnext = (t & 1) ? ridx0 : ridx1;        // L_{t+1}
        const int n = aload(&cnt[t]);
        for (int tile = blockIdx.x; tile * TMF < n; tile += gridDim.x)
            midfin_tile(As[0], As[1], Bs[0], Bs[1], tid,
                        Snew, P, bias_p, W_halt, W2, b2,
                        outp, p_sum, rprev, rnext, cnt, t, tile * TMF, n);
        if (t == MAX_ITER - 1) break;
        ++phase; gbar(bar, phase, tid);          // publish cnt[t+1], ridx, p_sum
        const int n1 = aload(&cnt[t + 1]);
        if (n1 == 0) break;                      // uniform across blocks
        {
            short* Sot = (t & 1) ? S1 : S0;
            const int ntiles = ((n1 + TM - 1) / TM) * (NGATES / TN);
            for (int e = blockIdx.x; e < ntiles; e += gridDim.x)
                gates_tile(As[0], Bs[0], tid, Snew, XB, Wg, bias_g, cell, Sot,
                           rnext, n1, (e >> 5) * TM, e & 31);
        }
        ++phase; gbar(bar, phase, tid);          // publish Sout, cell
        ++t;
    }
}

// R19 setup: x4 VECTORIZED weight packing (float4 in, short4 out).
// NOTE: S0/S1/cell are deliberately NOT initialized — at t=0 all rows are
// active, so gates(0) writes every state/cell entry before any read.
#define SETUP_XB4   (BATCH * IN_DIM / 4)
#define SETUP_WG4   (NGATES * (KTOT / 4))
#define SETUP_P4    (NP * (HID / 4))
#define SETUP_TOT4  (SETUP_XB4 + SETUP_WG4 + SETUP_P4)
__global__ __launch_bounds__(256) void setup_k(
    const float* __restrict__ x,
    const float* __restrict__ Whi, const float* __restrict__ Whf,
    const float* __restrict__ Whc, const float* __restrict__ Who,
    const float* __restrict__ Wxi, const float* __restrict__ Wxf,
    const float* __restrict__ Wxc, const float* __restrict__ Wxo,
    const float* __restrict__ bxi, const float* __restrict__ bhi,
    const float* __restrict__ bxf, const float* __restrict__ bhf,
    const float* __restrict__ bxc, const float* __restrict__ bhc,
    const float* __restrict__ bxo, const float* __restrict__ bho,
    const float* __restrict__ W1, const float* __restrict__ b1,
    const float* __restrict__ W_halt, const float* __restrict__ b_halt,
    short* __restrict__ XB,
    float* __restrict__ p_sum,
    int* __restrict__ ridx0, int* __restrict__ ridx1, int* __restrict__ cnt,
    int* __restrict__ bar, float* __restrict__ outp,
    short* __restrict__ Wg, float* __restrict__ bias_g,
    short* __restrict__ P, float* __restrict__ bias_p)
{
    int idx = blockIdx.x * 256 + threadIdx.x;
    if (idx < SETUP_XB4) {
        const int row = idx >> 4, k4 = (idx & 15) * 4;
        const float4f v = *(const float4f*)(x + row * IN_DIM + k4);
        short4v o;
#pragma unroll
        for (int e = 0; e < 4; ++e) o[e] = f2bf(v[e]);
        *(short4v*)(XB + row * IN_DIM + k4) = o;
        if (k4 == 0) {
            p_sum[row] = 0.f;
            outp[row] = 0.f;
            ridx0[row] = row;   // step 0: identity compaction
            ridx1[row] = 0;     // in-range dummies for padded tile reads
        }
        if (idx == 0) {
            for (int k = 0; k <= MAX_ITER; ++k) cnt[k] = (k == 0) ? BATCH : 0;
            bar[0] = 0;
        }
        return;
    }
    idx -= SETUP_XB4;
    if (idx < SETUP_WG4) {
        const int n = idx / (KTOT / 4), k4 = (idx - n * (KTOT / 4)) * 4;
        // interleaved layout: n = 64*G + 16*g + q  ->  gate g of hidden h=16*G+q
        const int G = n >> 6, g = (n >> 4) & 3, qq = n & 15;
        const int h = G * 16 + qq;
        const float* Wh = (g == 0) ? Whi : (g == 1) ? Whf : (g == 2) ? Whc : Who;
        const float* Wx = (g == 0) ? Wxi : (g == 1) ? Wxf : (g == 2) ? Wxc : Wxo;
        const float4f v = (k4 < HID)
            ? *(const float4f*)(Wh + h * HID + k4)
            : *(const float4f*)(Wx + h * IN_DIM + (k4 - HID));
        short4v o;
#pragma unroll
        for (int e = 0; e < 4; ++e) o[e] = f2bf(v[e]);
        *(short4v*)(Wg + (size_t)n * KTOT + k4) = o;
        if (k4 == 0) {
            const float* bx = (g == 0) ? bxi : (g == 1) ? bxf : (g == 2) ? bxc : bxo;
            const float* bh = (g == 0) ? bhi : (g == 1) ? bhf : (g == 2) ? bhc : bho;
            bias_g[n] = bx[h] + bh[h];
        }
        return;
    }
    idx -= SETUP_WG4;
    if (idx < SETUP_P4) {
        const int n = idx >> 8, k4 = (idx & 255) * 4;
        float4f v;
        if (n < OMID)      v = *(const float4f*)(W1 + n * HID + k4);
        else if (n == OMID) v = *(const float4f*)(W_halt + k4);
        else { v[0] = 0.f; v[1] = 0.f; v[2] = 0.f; v[3] = 0.f; }
        short4v o;
#pragma unroll
        for (int e = 0; e < 4; ++e) o[e] = f2bf(v[e]);
        *(short4v*)(P + (size_t)n * HID + k4) = o;
        if (k4 == 0) bias_p[n] = (n < OMID) ? b1[n] : (n == OMID ? b_halt[0] : 0.f);
    }
}

extern "C" void kernel_launch(void* const* d_in, const int* in_sizes, int n_in,
                              void* d_out, int out_size, void* d_ws, size_t ws_size,
                              hipStream_t stream) {
    const float* x    = (const float*)d_in[0];
    const float* Wxi  = (const float*)d_in[1];
    const float* bxi  = (const float*)d_in[2];
    const float* Whi  = (const float*)d_in[3];
    const float* bhi  = (const float*)d_in[4];
    const float* Wxf  = (const float*)d_in[5];
    const float* bxf  = (const float*)d_in[6];
    const float* Whf  = (const float*)d_in[7];
    const float* bhf  = (const float*)d_in[8];
    const float* Wxc  = (const float*)d_in[9];
    const float* bxc  = (const float*)d_in[10];
    const float* Whc  = (const float*)d_in[11];
    const float* bhc  = (const float*)d_in[12];
    const float* Wxo  = (const float*)d_in[13];
    const float* bxo  = (const float*)d_in[14];
    const float* Who  = (const float*)d_in[15];
    const float* bho  = (const float*)d_in[16];
    const float* W_halt = (const float*)d_in[17];
    const float* b_halt = (const float*)d_in[18];
    const float* W1   = (const float*)d_in[19];
    const float* b1   = (const float*)d_in[20];
    const float* W2   = (const float*)d_in[21];
    const float* b2   = (const float*)d_in[22];

    char* p = (char*)d_ws;
    auto carve = [&](size_t bytes) { char* r = p; p += (bytes + 255) & ~(size_t)255; return r; };
    short* S0     = (short*)carve((size_t)BATCH * HID * 2);
    short* S1     = (short*)carve((size_t)BATCH * HID * 2);
    short* XB     = (short*)carve((size_t)BATCH * IN_DIM * 2);
    short* Wg     = (short*)carve((size_t)NGATES * KTOT * 2);
    float* bias_g = (float*)carve((size_t)NGATES * 4);
    short* P      = (short*)carve((size_t)NP * HID * 2);
    float* bias_p = (float*)carve((size_t)NP * 4);
    float* cell   = (float*)carve((size_t)BATCH * HID * 4);
    float* p_sum  = (float*)carve((size_t)BATCH * 4);
    int*   ridx0  = (int*)carve((size_t)BATCH * 4);
    int*   ridx1  = (int*)carve((size_t)BATCH * 4);
    int*   cnt    = (int*)carve((size_t)(MAX_ITER + 1) * 4);
    int*   bar    = (int*)carve(256);
    float* outp   = (float*)d_out;

    setup_k<<<(SETUP_TOT4 + 255) / 256, 256, 0, stream>>>(
        x, Whi, Whf, Whc, Who, Wxi, Wxf, Wxc, Wxo,
        bxi, bhi, bxf, bhf, bxc, bhc, bxo, bho,
        W1, b1, W_halt, b_halt,
        XB, p_sum, ridx0, ridx1, cnt, bar, outp,
        Wg, bias_g, P, bias_p);

    // t=0: state==0 -> x-part only (1 k-iter from XB), cell write-only
    gates_k<<<dim3(16, 16), 512, 0, stream>>>(
        S0, XB, Wg + HID, bias_g, 1, 0, 1, cell, S1, ridx0, cnt, 0);
    midfin_k<<<512, 256, 0, stream>>>(
        S1, P, bias_p, W_halt, W2, b2, outp, p_sum, ridx0, ridx1, cnt, 0);
    // t=1: full batch
    gates_k<<<dim3(16, 16), 512, 0, stream>>>(
        S1, XB, Wg, bias_g, KTOT / TK, HID, 0, cell, S0, ridx1, cnt, 1);
    midfin_k<<<512, 256, 0, stream>>>(
        S0, P, bias_p, W_halt, W2, b2, outp, p_sum, ridx1, ridx0, cnt, 1);
    // t=2: ~half batch
    gates_k<<<dim3(16, 16), 512, 0, stream>>>(
        S0, XB, Wg, bias_g, KTOT / TK, HID, 0, cell, S1, ridx0, cnt, 2);
    midfin_k<<<512, 256, 0, stream>>>(
        S1, P, bias_p, W_halt, W2, b2, outp, p_sum, ridx0, ridx1, cnt, 2);
    // steps 3..7 (empty for this data) in one persistent 64-block kernel
    tail_k<<<TAILB, 256, 0, stream>>>(
        Wg, bias_g, P, bias_p, W_halt, W2, b2,
        S0, S1, XB, cell, outp, p_sum, ridx0, ridx1, cnt, bar);
}

// Round 12
// 404.606 us; speedup vs baseline: 1.1480x; 1.0037x over previous
//
#include <hip/hip_runtime.h>
#include <hip/hip_bf16.h>

#define BATCH 8192
#define IN_DIM 64
#define HID 1024
#define KTOT 1088   // HID + IN_DIM (fused K; weights laid out [n][KTOT])
#define NGATES 4096 // 4*HID, column c = 64*G + 16*g + q -> gate g of h=16*G+q
#define OMID 128
#define NP 256      // packed P rows (W1 0..127, W_halt 128, zeros)
#define MAX_ITER 8

#define TM 128
#define TN 128
#define TK 64
#define TMF 16      // midfin m-tile (R21: 16 rows -> 512 tiles = 2 blocks/CU)
#define NBH 144     // midfin Bs rows: 128 W1 + 16 (W_halt @128 + zeros)
#define GTM 256     // gates_k m-tile
#define GTN 256     // gates_k n-tile
#define TAILB 64    // tail_k blocks: few enough that a device barrier is cheap

typedef __attribute__((ext_vector_type(8))) short short8;
typedef __attribute__((ext_vector_type(4))) float float4v;
typedef __attribute__((ext_vector_type(4))) float float4f;
typedef __attribute__((ext_vector_type(4))) short short4v;

__device__ __forceinline__ float bf2f(short s) {
    union { float f; unsigned u; } v; v.u = ((unsigned)(unsigned short)s) << 16; return v.f;
}
__device__ __forceinline__ short f2bf(float f) {
    union { float f; unsigned u; } v; v.f = f;
    unsigned r = v.u + 0x7fff + ((v.u >> 16) & 1);  // round-to-nearest-even
    return (short)(r >> 16);
}
__device__ __forceinline__ float sigmoidf_(float x) {
    float xc = fminf(fmaxf(x, -30.f), 30.f);
    return 1.f / (1.f + __expf(-xc));
}
__device__ __forceinline__ float tanhf_(float x) {
    float xc = fminf(fmaxf(x, -15.f), 15.f);
    float e = __expf(2.f * xc);
    return (e - 1.f) / (e + 1.f);
}
__device__ __forceinline__ int aload(const int* p) {
    return __hip_atomic_load((int*)p, __ATOMIC_RELAXED, __HIP_MEMORY_SCOPE_AGENT);
}
__device__ __forceinline__ void astore(int* p, int v) {
    __hip_atomic_store(p, v, __ATOMIC_RELAXED, __HIP_MEMORY_SCOPE_AGENT);
}

// 64-block generation barrier (R8-verified; R5/R7/R11: ANY wider barrier
// pays 50-100us in cross-XCD L2 invalidate traffic). RELAXED polling by one
// lane per block with s_sleep; fences only at the crossing points.
__device__ __forceinline__ void gbar(int* bar, int phase, int tid) {
    __syncthreads();
    if (tid == 0) {
        __threadfence();
        __hip_atomic_fetch_add(bar, 1, __ATOMIC_ACQ_REL, __HIP_MEMORY_SCOPE_AGENT);
        while (aload(bar) < TAILB * phase)
            __builtin_amdgcn_s_sleep(8);
        __threadfence();
    }
    __syncthreads();
}

// Shared epilogue: fused LSTM cell update for one 128-row m-tile's
// accumulators (used by the 128^2 gates_tile inside tail_k).
// first=1 (t==0): cell is write-only (c = i*cg == f*0 + i*cg bit-exactly),
// so cell never needs zero-init and t=0 skips the 33.6MB cell read.
__device__ __forceinline__ void gates_epilogue(
    const float4v (&acc)[4][4], int m0, int bx, int wave, int lane, int first,
    const float* __restrict__ bias_g, float* __restrict__ cell,
    short* __restrict__ Sout, const int* __restrict__ ridx, int n_act)
{
    const int wm = wave & 1, wn = wave >> 1;
    const int colq = lane & 15, q = lane >> 4;
    const int G = bx * 2 + wn;   // 64-col group = 16 hidden units
    const int h = G * 16 + colq;
    const float bi  = bias_g[G * 64 +  0 + colq];
    const float bff = bias_g[G * 64 + 16 + colq];
    const float bc  = bias_g[G * 64 + 32 + colq];
    const float bo  = bias_g[G * 64 + 48 + colq];
#pragma unroll
    for (int i = 0; i < 4; ++i) {
        const int pbase = m0 + wm * 64 + i * 16 + q * 4;
#pragma unroll
        for (int r = 0; r < 4; ++r) {
            const int pos = pbase + r;
            if (pos < n_act) {
                const int row = ridx[pos];
                const float ig = sigmoidf_(acc[i][0][r] + bi);
                const float fg = sigmoidf_(acc[i][1][r] + bff);
                const float cg = tanhf_(acc[i][2][r] + bc);
                const float og = sigmoidf_(acc[i][3][r] + bo);
                const size_t ci = (size_t)row * HID + h;
                const float c = first ? (ig * cg) : (fg * cell[ci] + ig * cg);
                cell[ci] = c;
                Sout[(size_t)row * HID + h] = f2bf(og * tanhf_(c));
            }
        }
    }
}

// Gates GEMM, R23 = R21 form (best measured: total 404.5/406.1us, this
// kernel 116.5-116.8us). Closed experiments: (a) schedules — 2-block
// lockstep 127, 2-phase dbuf 116.5, zero-wait async 121.9, 4-phase 122.5,
// 4-phase double-fenced 120.5: all 575-627 TF; (b) occupancy/operand-path
// (R22) — 128^2 4-wave + B-from-global: occupancy 21->31% as predicted but
// 184us (FETCH +30MB: B panels not L2-resident under multi-block
// contention; B-loads coupled to MFMA consumption = exposed L2 latency).
// LDS staging + the R14 2-phase body is the verified fixed point.
// XCD-rectangle swizzle kept (FETCH 95->69 MB verified, time-neutral).
__global__ __launch_bounds__(512, 1) void gates_k(
    const short* __restrict__ S, const short* __restrict__ XB,
    const short* __restrict__ B,
    const float* __restrict__ bias_g, int nK, int hidK, int first,
    float* __restrict__ cell, short* __restrict__ Sout,
    const int* __restrict__ ridx, const int* __restrict__ cnt, int t)
{
    __shared__ short As[2][GTM * TK];   // 2 x 32 KiB
    __shared__ short Bs[2][GTN * TK];   // 2 x 32 KiB
    const int n_act = cnt[t];
    const int tid  = threadIdx.x;
    const int wave = tid >> 6, lane = tid & 63;
    const int wm2 = wave >> 2, wn4 = wave & 3;   // wave -> 128-row half x 64-col quarter
    const int colq = lane & 15, q = lane >> 4;
    const int lrow8 = lane >> 3;
    const int lk    = (((lane & 7) ^ lrow8) * 8);   // pre-swizzled source offset
    const int xq = colq & 7;
    const int abase = (wm2 * 128 + colq) * TK;   // shorts
    const int bbase = (wn4 * 64  + colq) * TK;   // shorts

    // XCD-rectangle swizzle (grid is 16x16 for all gates_k launches).
    int bx, byS;
    {
        const int lin  = (int)blockIdx.x + 16 * (int)blockIdx.y;  // hw order
        const int xcd  = lin & 7;          // round-robin XCD assignment
        const int slot = lin >> 3;         // 0..31 within this XCD
        bx  = (xcd & 1) * 8 + (slot & 7);  // 8 consecutive x per XCD
        byS = (xcd >> 1) * 4 + (slot >> 3);// 4 consecutive y per XCD
    }
    const int n0 = bx * GTN;

    for (int by = byS; by * GTM < n_act; by += 16) {
        const int m0 = by * GTM;

        // per-wave staged rows: wave*32 + it*8 + lrow8 (A and B share the map)
        int rows_[4];
        const short* gb[4];
#pragma unroll
        for (int it = 0; it < 4; ++it) {
            const int rr = wave * 32 + it * 8 + lrow8;
            rows_[it] = ridx[m0 + rr];
            gb[it] = B + (size_t)(n0 + rr) * KTOT + lk;
        }

        float4v acc[8][4];
#pragma unroll
        for (int i = 0; i < 8; ++i)
#pragma unroll
            for (int j = 0; j < 4; ++j) acc[i][j] = (float4v)0.f;

        auto stage = [&](int ki, int buf) {
            const int kk = ki * TK;
            const bool fromS = (kk < hidK);   // kernel-uniform branch
#pragma unroll
            for (int it = 0; it < 4; ++it) {
                const int dst = (wave * 32 + it * 8) * TK;
                const short* sa = fromS
                    ? (S  + (size_t)rows_[it] * HID    + kk + lk)
                    : (XB + (size_t)rows_[it] * IN_DIM + lk);
                __builtin_amdgcn_global_load_lds(
                    (const __attribute__((address_space(1))) void*)sa,
                    (__attribute__((address_space(3))) void*)(As[buf] + dst), 16, 0, 0);
                __builtin_amdgcn_global_load_lds(
                    (const __attribute__((address_space(1))) void*)(gb[it] + kk),
                    (__attribute__((address_space(3))) void*)(Bs[buf] + dst), 16, 0, 0);
            }
        };

        stage(0, 0);
        __syncthreads();   // drains prologue stage

        for (int ki = 0; ki < nK; ++ki) {
            const int cur = ki & 1;
            if (ki + 1 < nK) stage(ki + 1, cur ^ 1);   // issue BEFORE compute
            const short* Ac = As[cur];
            const short* Bc = Bs[cur];
#pragma unroll
            for (int c2 = 0; c2 < 2; ++c2) {
                const int xt = ((q + 4 * c2) ^ xq) << 3;
                short8 af[8], bf[4];
#pragma unroll
                for (int i = 0; i < 8; ++i)
                    af[i] = *(const short8*)(Ac + abase + i * (16 * TK) + xt);
#pragma unroll
                for (int j = 0; j < 4; ++j)
                    bf[j] = *(const short8*)(Bc + bbase + j * (16 * TK) + xt);
#pragma unroll
                for (int i = 0; i < 8; ++i)
#pragma unroll
                    for (int j = 0; j < 4; ++j)
                        acc[i][j] = __builtin_amdgcn_mfma_f32_16x16x32_bf16(af[i], bf[j], acc[i][j], 0, 0, 0);
            }
            // one barrier per K-step: lgkm (ds_reads) drained by MFMA deps,
            // vmcnt drained inside __syncthreads -> buf[cur^1] ready.
            __syncthreads();
        }

        // epilogue: per wave, cols n0 + wn4*64 .. +63 = one 64-col G-group
        // = all 4 gates of 16 hidden units (interleaved weight layout).
        const int G = bx * 4 + wn4;
        const int h = G * 16 + colq;
        const float bi  = bias_g[G * 64 +  0 + colq];
        const float bff = bias_g[G * 64 + 16 + colq];
        const float bc  = bias_g[G * 64 + 32 + colq];
        const float bo  = bias_g[G * 64 + 48 + colq];
#pragma unroll
        for (int i = 0; i < 8; ++i) {
            const int pbase = m0 + wm2 * 128 + i * 16 + q * 4;
#pragma unroll
            for (int r = 0; r < 4; ++r) {
                const int pos = pbase + r;
                if (pos < n_act) {
                    const int row = ridx[pos];
                    const float ig = sigmoidf_(acc[i][0][r] + bi);
                    const float fg = sigmoidf_(acc[i][1][r] + bff);
                    const float cg = tanhf_(acc[i][2][r] + bc);
                    const float og = sigmoidf_(acc[i][3][r] + bo);
                    const size_t ci = (size_t)row * HID + h;
                    const float c = first ? (ig * cg) : (fg * cell[ci] + ig * cg);
                    cell[ci] = c;
                    Sout[(size_t)row * HID + h] = f2bf(og * tanhf_(c));
                }
            }
        }
        // last K-iter ended in __syncthreads; epilogue touches no LDS;
        // next m-tile's stage(0,0) is followed by its own __syncthreads.
    }
}

// Single-m-tile gates (R10 form, split-A, 128^2) — used only inside tail_k.
__device__ __forceinline__ void gates_tile(
    short* As, short* Bs, int tid,
    const short* __restrict__ S, const short* __restrict__ XB,
    const short* __restrict__ B,
    const float* __restrict__ bias_g,
    float* __restrict__ cell, short* __restrict__ Sout,
    const int* __restrict__ ridx, int n_act, int m0, int bx)
{
    const int wave = tid >> 6, lane = tid & 63;
    const int wm = wave & 1, wn = wave >> 1;
    const int colq = lane & 15, q = lane >> 4;
    const int lrow8 = lane >> 3;
    const int lk    = (((lane & 7) ^ lrow8) * 8);
    const int n0 = bx * TN;

    int aoff[4][2], boff[4][2];
#pragma unroll
    for (int i = 0; i < 4; ++i) {
        const int Ra = wm * 64 + i * 16 + colq;
        const int Rb = wn * 64 + i * 16 + colq;
#pragma unroll
        for (int c2 = 0; c2 < 2; ++c2) {
            const int C = q + 4 * c2;
            aoff[i][c2] = Ra * TK + ((C ^ (Ra & 7)) << 3);
            boff[i][c2] = Rb * TK + ((C ^ (Rb & 7)) << 3);
        }
    }

    float4v acc[4][4];
#pragma unroll
    for (int i = 0; i < 4; ++i)
#pragma unroll
        for (int j = 0; j < 4; ++j) acc[i][j] = (float4v)0.f;

    const short* gaS[4];
    const short* gaX[4];
    const short* gb[4];
#pragma unroll
    for (int it = 0; it < 4; ++it) {
        const int rr = (wave * 4 + it) * 8;
        const int r0 = ridx[m0 + rr + lrow8];
        gaS[it] = S + (size_t)r0 * HID + lk;
        gaX[it] = XB + (size_t)r0 * IN_DIM + lk;
        gb[it]  = B + (size_t)(n0 + rr + lrow8) * KTOT + lk;
    }

    for (int ki = 0; ki < KTOT / TK; ++ki) {
        const bool fromS = (ki * TK < HID);
#pragma unroll
        for (int it = 0; it < 4; ++it) {
            const int rr = (wave * 4 + it) * 8;
            const short* a0 = fromS ? gaS[it] : gaX[it];
            __builtin_amdgcn_global_load_lds(
                (const __attribute__((address_space(1))) void*)a0,
                (__attribute__((address_space(3))) void*)(As + rr * TK), 16, 0, 0);
            __builtin_amdgcn_global_load_lds(
                (const __attribute__((address_space(1))) void*)gb[it],
                (__attribute__((address_space(3))) void*)(Bs + rr * TK), 16, 0, 0);
            gaS[it] += TK; gb[it] += TK;
        }
        __syncthreads();
#pragma unroll
        for (int c2 = 0; c2 < 2; ++c2) {
            short8 af[4], bf[4];
#pragma unroll
            for (int i = 0; i < 4; ++i) {
                af[i] = *(const short8*)(As + aoff[i][c2]);
                bf[i] = *(const short8*)(Bs + boff[i][c2]);
            }
#pragma unroll
            for (int i = 0; i < 4; ++i)
#pragma unroll
                for (int j = 0; j < 4; ++j)
                    acc[i][j] = __builtin_amdgcn_mfma_f32_16x16x32_bf16(af[i], bf[j], acc[i][j], 0, 0, 0);
        }
        __syncthreads();
    }

    gates_epilogue(acc, m0, bx, wave, lane, 0, bias_g, cell, Sout, ridx, n_act);
    __syncthreads();   // protect As/Bs before caller's next tile
}

// R21 midfin + R24 ORDERED COMPACTION. The per-row atomicAdd compaction
// produced a RANDOM permutation in rnext -> every later A-gather (gates
// staging, midfin A-reads) touched random 2KB rows: L2 (4MB/XCD vs S=16MB)
// thrashes and HBM serves 64B lines for 16B used. t=1 FETCH arithmetic:
// ideal reads Wg 8.9 + S 16 + cell 32 = 57MB, measured 69MB = ~12MB gather
// over-fetch on that dispatch alone (plus t=2 + 3 midfins unmeasured).
// R24: wave-ballot ordered compaction — lanes 0..15 ballot survivors,
// lane 0 reserves a contiguous range (ONE atomicAdd of popcount), each
// survivor writes at base + popcount(mask below). rnext becomes contiguous
// ascending 16-row runs -> 32KB-contiguous gathers. Numerics identical:
// all computation is row-indexed; only list ORDER changes.
__device__ __forceinline__ void midfin_tile(
    short* As0, short* As1, short* Bs0, short* Bs1, int tid,
    const short* __restrict__ Snew, const short* __restrict__ P,
    const float* __restrict__ bias_p, const float* __restrict__ W_halt,
    const float* __restrict__ W2, const float* __restrict__ b2,
    float* __restrict__ outp, float* __restrict__ p_sum,
    const int* __restrict__ rprev, int* __restrict__ rnext,
    int* __restrict__ cnt, int t, int m0, int n_act)
{
    const int wave = tid >> 6, lane = tid & 63;
    const int colq = lane & 15, q = lane >> 4;
    const int lrow8 = lane >> 3;
    const int lk    = (((lane & 7) ^ lrow8) * 8);
    const int xq = colq & 7;

    float4v acc[2];
    acc[0] = (float4v)0.f; acc[1] = (float4v)0.f;
    float4v acc_h = (float4v)0.f;

    // per-lane source rows (rows beyond n_act read stale-but-in-range ridx
    // entries -> safe dummy gathers, results masked at finalize)
    const int arow_ = (wave < 2) ? rprev[m0 + wave * 8 + lrow8] : 0;
    const short* ga = Snew + (size_t)arow_ * HID + lk;
    const short* gbp[4];
#pragma unroll
    for (int g = 0; g < 4; ++g)
        gbp[g] = P + (size_t)(wave * 32 + g * 8 + lrow8) * HID + lk;
    const short* gbh[2];
#pragma unroll
    for (int l = 0; l < 2; ++l)
        gbh[l] = P + (size_t)(128 + l * 8 + lrow8) * HID + lk;

    auto stage = [&](int ks, short* Asb, short* Bsb) {
        const int k0 = ks * TK;
        if (wave < 2)   // wave-uniform: A rows wave*8..+7
            __builtin_amdgcn_global_load_lds(
                (const __attribute__((address_space(1))) void*)(ga + k0),
                (__attribute__((address_space(3))) void*)(Asb + (wave * 8) * TK), 16, 0, 0);
#pragma unroll
        for (int g = 0; g < 4; ++g)
            __builtin_amdgcn_global_load_lds(
                (const __attribute__((address_space(1))) void*)(gbp[g] + k0),
                (__attribute__((address_space(3))) void*)(Bsb + (wave * 32 + g * 8) * TK), 16, 0, 0);
        if (wave == 3)  // wave-uniform: halt rows 128..143
#pragma unroll
            for (int l = 0; l < 2; ++l)
                __builtin_amdgcn_global_load_lds(
                    (const __attribute__((address_space(1))) void*)(gbh[l] + k0),
                    (__attribute__((address_space(3))) void*)(Bsb + (128 + l * 8) * TK), 16, 0, 0);
    };

    stage(0, As0, Bs0);
    __syncthreads();   // drains prologue stage

    for (int ks = 0; ks < HID / TK; ++ks) {
        const int cur = ks & 1;
        if (ks + 1 < HID / TK)   // issue next stage BEFORE compute
            stage(ks + 1, cur ? As0 : As1, cur ? Bs0 : Bs1);
        const short* Asb = cur ? As1 : As0;
        const short* Bsb = cur ? Bs1 : Bs0;
#pragma unroll
        for (int c2 = 0; c2 < 2; ++c2) {
            const int xt = ((q + 4 * c2) ^ xq) << 3;
            const short8 af = *(const short8*)(Asb + colq * TK + xt);
            const short8 bf0 = *(const short8*)(Bsb + (wave * 32 + colq) * TK + xt);
            const short8 bf1 = *(const short8*)(Bsb + (wave * 32 + 16 + colq) * TK + xt);
            acc[0] = __builtin_amdgcn_mfma_f32_16x16x32_bf16(af, bf0, acc[0], 0, 0, 0);
            acc[1] = __builtin_amdgcn_mfma_f32_16x16x32_bf16(af, bf1, acc[1], 0, 0, 0);
            if (wave == 0) {   // halt fragment: B rows 128..143
                const short8 bh = *(const short8*)(Bsb + (128 + colq) * TK + xt);
                acc_h = __builtin_amdgcn_mfma_f32_16x16x32_bf16(af, bh, acc_h, 0, 0, 0);
            }
        }
        __syncthreads();   // reads retired (lgkm) + next stage landed (vmcnt)
    }

    // aliases over As0 (k-loop done; last barrier above protects)
    float* red  = (float*)As0;          // 64 floats: [w][q][r]
    float* hbuf = ((float*)As0) + 64;   // 16 floats

    // halt values: wave 0's col-0 lanes hold state.W_halt for row q*4+r
    if (wave == 0 && colq == 0) {
#pragma unroll
        for (int r = 0; r < 4; ++r)
            hbuf[q * 4 + r] = acc_h[r];
    }

    // relu + W2-dot over this wave's 32 cols, reduce over colq
    float pr[4];
#pragma unroll
    for (int r = 0; r < 4; ++r) pr[r] = 0.f;
#pragma unroll
    for (int nj = 0; nj < 2; ++nj) {
        const int col = wave * 32 + nj * 16 + colq;
        const float b = bias_p[col];
        const float w2 = W2[col];
#pragma unroll
        for (int r = 0; r < 4; ++r)
            pr[r] += fmaxf(acc[nj][r] + b, 0.f) * w2;
    }
#pragma unroll
    for (int r = 0; r < 4; ++r) {
        float v = pr[r];
        v += __shfl_down(v, 8, 16);
        v += __shfl_down(v, 4, 16);
        v += __shfl_down(v, 2, 16);
        v += __shfl_down(v, 1, 16);
        if (colq == 0)
            red[(wave * 4 + q) * 4 + r] = v;
    }
    __syncthreads();

    // finalize: lanes 0..15 of wave 0, one per row; ORDERED compaction.
    if (tid < TMF) {
        const int pos = m0 + tid;
        bool alive = false;
        int row = 0;
        if (pos < n_act) {
            const int lq = tid >> 2, r = tid & 3;
            float odot = 0.f;
#pragma unroll
            for (int w = 0; w < 4; ++w)
                odot += red[(w * 4 + lq) * 4 + r];
            row = rprev[pos];
            const float ov = sigmoidf_(odot + b2[0]);
            const float h  = sigmoidf_(hbuf[tid] + bias_p[OMID]);
            const float ps = p_sum[row];
            const float pn = ps + h;
            const bool fin = (pn >= 1.f - 1e-3f) || (t == MAX_ITER - 1);
            const float halt = fin ? (1.f - ps) : h;
            outp[row] += ov * halt;
            p_sum[row] = fin ? 1.f : pn;
            alive = !fin;
        }
        // ballot over active lanes (0..15); higher lanes contribute no bits.
        const unsigned long long m = __ballot(alive);
        int base = 0;
        if (tid == 0 && m)
            base = atomicAdd(&cnt[t + 1], __popcll(m));
        base = __shfl(base, 0);   // lane 0 is always active here
        if (alive) {
            const int off = __popcll(m & ((1ull << tid) - 1ull));
            astore(&rnext[base + off], row);
        }
    }
    __syncthreads();   // protect As/Bs aliases before caller reuses LDS
}

// Standalone midfin dispatch (steps 0..2): 512 blocks x 16-row tiles.
__global__ __launch_bounds__(256) void midfin_k(
    const short* __restrict__ Snew, const short* __restrict__ P,
    const float* __restrict__ bias_p, const float* __restrict__ W_halt,
    const float* __restrict__ W2, const float* __restrict__ b2,
    float* __restrict__ outp, float* __restrict__ p_sum,
    const int* __restrict__ rprev, int* __restrict__ rnext,
    int* __restrict__ cnt, int t)
{
    __shared__ short As[2][TMF * TK];   // 2 x 2 KiB
    __shared__ short Bs[2][NBH * TK];   // 2 x 18 KiB
    const int n_act = cnt[t];
    for (int tile = blockIdx.x; tile * TMF < n_act; tile += gridDim.x)
        midfin_tile(As[0], As[1], Bs[0], Bs[1], threadIdx.x,
                    Snew, P, bias_p, W_halt, W2, b2,
                    outp, p_sum, rprev, rnext, cnt, t, tile * TMF, n_act);
}

// Persistent 64-block tail: steps 3..7 (midfin+gates) with in-kernel
// barriers. For this data cnt[3]==0 so it exits after one gbar; full loop
// retained for arbitrary data.
__global__ __launch_bounds__(256) void tail_k(
    const short* __restrict__ Wg, const float* __restrict__ bias_g,
    const short* __restrict__ P, const float* __restrict__ bias_p,
    const float* __restrict__ W_halt, const float* __restrict__ W2,
    const float* __restrict__ b2,
    short* __restrict__ S0, short* __restrict__ S1,
    const short* __restrict__ XB,
    float* __restrict__ cell, float* __restrict__ outp,
    float* __restrict__ p_sum,
    int* __restrict__ ridx0, int* __restrict__ ridx1,
    int* __restrict__ cnt, int* __restrict__ bar)
{
    __shared__ short As[2][TM * TK];    // gates_tile uses As[0]/Bs[0] flat
    __shared__ short Bs[2][NBH * TK];   // (NBH*TK = 9216 >= TN*TK = 8192)
    const int tid = threadIdx.x;
    int phase = 0;
    int t = 3;
    while (true) {
        short* Snew = (t & 1) ? S0 : S1;        // state written by gates(t)
        const int* rprev = (t & 1) ? ridx1 : ridx0;  // L_t
        int* rnext = (t & 1) ? ridx0 : ridx1;        // L_{t+1}
        const int n = aload(&cnt[t]);
        for (int tile = blockIdx.x; tile * TMF < n; tile += gridDim.x)
            midfin_tile(As[0], As[1], Bs[0], Bs[1], tid,
                        Snew, P, bias_p, W_halt, W2, b2,
                        outp, p_sum, rprev, rnext, cnt, t, tile * TMF, n);
        if (t == MAX_ITER - 1) break;
        ++phase; gbar(bar, phase, tid);          // publish cnt[t+1], ridx, p_sum
        const int n1 = aload(&cnt[t + 1]);
        if (n1 == 0) break;                      // uniform across blocks
        {
            short* Sot = (t & 1) ? S1 : S0;
            const int ntiles = ((n1 + TM - 1) / TM) * (NGATES / TN);
            for (int e = blockIdx.x; e < ntiles; e += gridDim.x)
                gates_tile(As[0], Bs[0], tid, Snew, XB, Wg, bias_g, cell, Sot,
                           rnext, n1, (e >> 5) * TM, e & 31);
        }
        ++phase; gbar(bar, phase, tid);          // publish Sout, cell
        ++t;
    }
}

// R19 setup: x4 VECTORIZED weight packing (float4 in, short4 out).
// NOTE: S0/S1/cell are deliberately NOT initialized — at t=0 all rows are
// active, so gates(0) writes every state/cell entry before any read.
#define SETUP_XB4   (BATCH * IN_DIM / 4)
#define SETUP_WG4   (NGATES * (KTOT / 4))
#define SETUP_P4    (NP * (HID / 4))
#define SETUP_TOT4  (SETUP_XB4 + SETUP_WG4 + SETUP_P4)
__global__ __launch_bounds__(256) void setup_k(
    const float* __restrict__ x,
    const float* __restrict__ Whi, const float* __restrict__ Whf,
    const float* __restrict__ Whc, const float* __restrict__ Who,
    const float* __restrict__ Wxi, const float* __restrict__ Wxf,
    const float* __restrict__ Wxc, const float* __restrict__ Wxo,
    const float* __restrict__ bxi, const float* __restrict__ bhi,
    const float* __restrict__ bxf, const float* __restrict__ bhf,
    const float* __restrict__ bxc, const float* __restrict__ bhc,
    const float* __restrict__ bxo, const float* __restrict__ bho,
    const float* __restrict__ W1, const float* __restrict__ b1,
    const float* __restrict__ W_halt, const float* __restrict__ b_halt,
    short* __restrict__ XB,
    float* __restrict__ p_sum,
    int* __restrict__ ridx0, int* __restrict__ ridx1, int* __restrict__ cnt,
    int* __restrict__ bar, float* __restrict__ outp,
    short* __restrict__ Wg, float* __restrict__ bias_g,
    short* __restrict__ P, float* __restrict__ bias_p)
{
    int idx = blockIdx.x * 256 + threadIdx.x;
    if (idx < SETUP_XB4) {
        const int row = idx >> 4, k4 = (idx & 15) * 4;
        const float4f v = *(const float4f*)(x + row * IN_DIM + k4);
        short4v o;
#pragma unroll
        for (int e = 0; e < 4; ++e) o[e] = f2bf(v[e]);
        *(short4v*)(XB + row * IN_DIM + k4) = o;
        if (k4 == 0) {
            p_sum[row] = 0.f;
            outp[row] = 0.f;
            ridx0[row] = row;   // step 0: identity compaction
            ridx1[row] = 0;     // in-range dummies for padded tile reads
        }
        if (idx == 0) {
            for (int k = 0; k <= MAX_ITER; ++k) cnt[k] = (k == 0) ? BATCH : 0;
            bar[0] = 0;
        }
        return;
    }
    idx -= SETUP_XB4;
    if (idx < SETUP_WG4) {
        const int n = idx / (KTOT / 4), k4 = (idx - n * (KTOT / 4)) * 4;
        // interleaved layout: n = 64*G + 16*g + q  ->  gate g of hidden h=16*G+q
        const int G = n >> 6, g = (n >> 4) & 3, qq = n & 15;
        const int h = G * 16 + qq;
        const float* Wh = (g == 0) ? Whi : (g == 1) ? Whf : (g == 2) ? Whc : Who;
        const float* Wx = (g == 0) ? Wxi : (g == 1) ? Wxf : (g == 2) ? Wxc : Wxo;
        const float4f v = (k4 < HID)
            ? *(const float4f*)(Wh + h * HID + k4)
            : *(const float4f*)(Wx + h * IN_DIM + (k4 - HID));
        short4v o;
#pragma unroll
        for (int e = 0; e < 4; ++e) o[e] = f2bf(v[e]);
        *(short4v*)(Wg + (size_t)n * KTOT + k4) = o;
        if (k4 == 0) {
            const float* bx = (g == 0) ? bxi : (g == 1) ? bxf : (g == 2) ? bxc : bxo;
            const float* bh = (g == 0) ? bhi : (g == 1) ? bhf : (g == 2) ? bhc : bho;
            bias_g[n] = bx[h] + bh[h];
        }
        return;
    }
    idx -= SETUP_WG4;
    if (idx < SETUP_P4) {
        const int n = idx >> 8, k4 = (idx & 255) * 4;
        float4f v;
        if (n < OMID)      v = *(const float4f*)(W1 + n * HID + k4);
        else if (n == OMID) v = *(const float4f*)(W_halt + k4);
        else { v[0] = 0.f; v[1] = 0.f; v[2] = 0.f; v[3] = 0.f; }
        short4v o;
#pragma unroll
        for (int e = 0; e < 4; ++e) o[e] = f2bf(v[e]);
        *(short4v*)(P + (size_t)n * HID + k4) = o;
        if (k4 == 0) bias_p[n] = (n < OMID) ? b1[n] : (n == OMID ? b_halt[0] : 0.f);
    }
}

extern "C" void kernel_launch(void* const* d_in, const int* in_sizes, int n_in,
                              void* d_out, int out_size, void* d_ws, size_t ws_size,
                              hipStream_t stream) {
    const float* x    = (const float*)d_in[0];
    const float* Wxi  = (const float*)d_in[1];
    const float* bxi  = (const float*)d_in[2];
    const float* Whi  = (const float*)d_in[3];
    const float* bhi  = (const float*)d_in[4];
    const float* Wxf  = (const float*)d_in[5];
    const float* bxf  = (const float*)d_in[6];
    const float* Whf  = (const float*)d_in[7];
    const float* bhf  = (const float*)d_in[8];
    const float* Wxc  = (const float*)d_in[9];
    const float* bxc  = (const float*)d_in[10];
    const float* Whc  = (const float*)d_in[11];
    const float* bhc  = (const float*)d_in[12];
    const float* Wxo  = (const float*)d_in[13];
    const float* bxo  = (const float*)d_in[14];
    const float* Who  = (const float*)d_in[15];
    const float* bho  = (const float*)d_in[16];
    const float* W_halt = (const float*)d_in[17];
    const float* b_halt = (const float*)d_in[18];
    const float* W1   = (const float*)d_in[19];
    const float* b1   = (const float*)d_in[20];
    const float* W2   = (const float*)d_in[21];
    const float* b2   = (const float*)d_in[22];

    char* p = (char*)d_ws;
    auto carve = [&](size_t bytes) { char* r = p; p += (bytes + 255) & ~(size_t)255; return r; };
    short* S0     = (short*)carve((size_t)BATCH * HID * 2);
    short* S1     = (short*)carve((size_t)BATCH * HID * 2);
    short* XB     = (short*)carve((size_t)BATCH * IN_DIM * 2);
    short* Wg     = (short*)carve((size_t)NGATES * KTOT * 2);
    float* bias_g = (float*)carve((size_t)NGATES * 4);
    short* P      = (short*)carve((size_t)NP * HID * 2);
    float* bias_p = (float*)carve((size_t)NP * 4);
    float* cell   = (float*)carve((size_t)BATCH * HID * 4);
    float* p_sum  = (float*)carve((size_t)BATCH * 4);
    int*   ridx0  = (int*)carve((size_t)BATCH * 4);
    int*   ridx1  = (int*)carve((size_t)BATCH * 4);
    int*   cnt    = (int*)carve((size_t)(MAX_ITER + 1) * 4);
    int*   bar    = (int*)carve(256);
    float* outp   = (float*)d_out;

    setup_k<<<(SETUP_TOT4 + 255) / 256, 256, 0, stream>>>(
        x, Whi, Whf, Whc, Who, Wxi, Wxf, Wxc, Wxo,
        bxi, bhi, bxf, bhf, bxc, bhc, bxo, bho,
        W1, b1, W_halt, b_halt,
        XB, p_sum, ridx0, ridx1, cnt, bar, outp,
        Wg, bias_g, P, bias_p);

    // t=0: state==0 -> x-part only (1 k-iter from XB), cell write-only
    gates_k<<<dim3(16, 16), 512, 0, stream>>>(
        S0, XB, Wg + HID, bias_g, 1, 0, 1, cell, S1, ridx0, cnt, 0);
    midfin_k<<<512, 256, 0, stream>>>(
        S1, P, bias_p, W_halt, W2, b2, outp, p_sum, ridx0, ridx1, cnt, 0);
    // t=1: full batch
    gates_k<<<dim3(16, 16), 512, 0, stream>>>(
        S1, XB, Wg, bias_g, KTOT / TK, HID, 0, cell, S0, ridx1, cnt, 1);
    midfin_k<<<512, 256, 0, stream>>>(
        S0, P, bias_p, W_halt, W2, b2, outp, p_sum, ridx1, ridx0, cnt, 1);
    // t=2: ~half batch
    gates_k<<<dim3(16, 16), 512, 0, stream>>>(
        S0, XB, Wg, bias_g, KTOT / TK, HID, 0, cell, S1, ridx0, cnt, 2);
    midfin_k<<<512, 256, 0, stream>>>(
        S1, P, bias_p, W_halt, W2, b2, outp, p_sum, ridx0, ridx1, cnt, 2);
    // steps 3..7 (empty for this data) in one persistent 64-block kernel
    tail_k<<<TAILB, 256, 0, stream>>>(
        Wg, bias_g, P, bias_p, W_halt, W2, b2,
        S0, S1, XB, cell, outp, p_sum, ridx0, ridx1, cnt, bar);
}

// Round 13
// 404.179 us; speedup vs baseline: 1.1492x; 1.0011x over previous
//
#include <hip/hip_runtime.h>
#include <hip/hip_bf16.h>

#define BATCH 8192
#define IN_DIM 64
#define HID 1024
#define KTOT 1088   // HID + IN_DIM (fused K; weights laid out [n][KTOT])
#define NGATES 4096 // 4*HID, column c = 64*G + 16*g + q -> gate g of h=16*G+q
#define OMID 128
#define NP 256      // packed P rows (W1 0..127, W_halt 128, zeros)
#define MAX_ITER 8

#define TM 128
#define TN 128
#define TK 64
#define TMF 16      // midfin m-tile (R21: 16 rows -> 512 tiles = 2 blocks/CU)
#define NBH 144     // midfin Bs rows: 128 W1 + 16 (W_halt @128 + zeros)
#define GTM 256     // gates_k m-tile
#define GTN 256     // gates_k n-tile
#define TAILB 64    // tail_k blocks: few enough that a device barrier is cheap

typedef __attribute__((ext_vector_type(8))) short short8;
typedef __attribute__((ext_vector_type(4))) float float4v;
typedef __attribute__((ext_vector_type(4))) float float4f;
typedef __attribute__((ext_vector_type(4))) short short4v;

__device__ __forceinline__ float bf2f(short s) {
    union { float f; unsigned u; } v; v.u = ((unsigned)(unsigned short)s) << 16; return v.f;
}
__device__ __forceinline__ short f2bf(float f) {
    union { float f; unsigned u; } v; v.f = f;
    unsigned r = v.u + 0x7fff + ((v.u >> 16) & 1);  // round-to-nearest-even
    return (short)(r >> 16);
}
__device__ __forceinline__ float sigmoidf_(float x) {
    float xc = fminf(fmaxf(x, -30.f), 30.f);
    return 1.f / (1.f + __expf(-xc));
}
__device__ __forceinline__ float tanhf_(float x) {
    float xc = fminf(fmaxf(x, -15.f), 15.f);
    float e = __expf(2.f * xc);
    return (e - 1.f) / (e + 1.f);
}
__device__ __forceinline__ int aload(const int* p) {
    return __hip_atomic_load((int*)p, __ATOMIC_RELAXED, __HIP_MEMORY_SCOPE_AGENT);
}
__device__ __forceinline__ void astore(int* p, int v) {
    __hip_atomic_store(p, v, __ATOMIC_RELAXED, __HIP_MEMORY_SCOPE_AGENT);
}

// 64-block generation barrier (R8-verified; R5/R7/R11: ANY wider barrier
// pays 50-100us in cross-XCD L2 invalidate traffic). RELAXED polling by one
// lane per block with s_sleep; fences only at the crossing points.
__device__ __forceinline__ void gbar(int* bar, int phase, int tid) {
    __syncthreads();
    if (tid == 0) {
        __threadfence();
        __hip_atomic_fetch_add(bar, 1, __ATOMIC_ACQ_REL, __HIP_MEMORY_SCOPE_AGENT);
        while (aload(bar) < TAILB * phase)
            __builtin_amdgcn_s_sleep(8);
        __threadfence();
    }
    __syncthreads();
}

// Shared epilogue: fused LSTM cell update for one 128-row m-tile's
// accumulators (used by the 128^2 gates_tile inside tail_k).
// first=1 (t==0): cell is write-only (c = i*cg == f*0 + i*cg bit-exactly),
// so cell never needs zero-init and t=0 skips the 33.6MB cell read.
__device__ __forceinline__ void gates_epilogue(
    const float4v (&acc)[4][4], int m0, int bx, int wave, int lane, int first,
    const float* __restrict__ bias_g, float* __restrict__ cell,
    short* __restrict__ Sout, const int* __restrict__ ridx, int n_act)
{
    const int wm = wave & 1, wn = wave >> 1;
    const int colq = lane & 15, q = lane >> 4;
    const int G = bx * 2 + wn;   // 64-col group = 16 hidden units
    const int h = G * 16 + colq;
    const float bi  = bias_g[G * 64 +  0 + colq];
    const float bff = bias_g[G * 64 + 16 + colq];
    const float bc  = bias_g[G * 64 + 32 + colq];
    const float bo  = bias_g[G * 64 + 48 + colq];
#pragma unroll
    for (int i = 0; i < 4; ++i) {
        const int pbase = m0 + wm * 64 + i * 16 + q * 4;
#pragma unroll
        for (int r = 0; r < 4; ++r) {
            const int pos = pbase + r;
            if (pos < n_act) {
                const int row = ridx[pos];
                const float ig = sigmoidf_(acc[i][0][r] + bi);
                const float fg = sigmoidf_(acc[i][1][r] + bff);
                const float cg = tanhf_(acc[i][2][r] + bc);
                const float og = sigmoidf_(acc[i][3][r] + bo);
                const size_t ci = (size_t)row * HID + h;
                const float c = first ? (ig * cg) : (fg * cell[ci] + ig * cg);
                cell[ci] = c;
                Sout[(size_t)row * HID + h] = f2bf(og * tanhf_(c));
            }
        }
    }
}

// Gates GEMM — FINAL (R14/R18/R21 form; 116.5-118us measured, stable
// across containers). Session-closed experiments: (a) five schedules —
// 2-block lockstep 127, 2-phase dbuf 116.5, zero-wait async 121.9,
// 4-phase 122.5, 4-phase double-fenced 120.5: all 575-627 TF,
// schedule-insensitive; (b) occupancy/operand-path (R22): 128^2 4-wave +
// B-from-global raised occupancy 21->31% as predicted but regressed to
// 184us (B not L2-resident under contention; B-load latency coupled to
// MFMA consumption); (c) gather ordering (R24): FETCH bit-identical ->
// the 69MB is structural single-visit traffic. LDS staging + the 2-phase
// dbuf body is the verified fixed point.
// XCD-rectangle swizzle kept (FETCH 95->69 MB verified, time-neutral).
__global__ __launch_bounds__(512, 1) void gates_k(
    const short* __restrict__ S, const short* __restrict__ XB,
    const short* __restrict__ B,
    const float* __restrict__ bias_g, int nK, int hidK, int first,
    float* __restrict__ cell, short* __restrict__ Sout,
    const int* __restrict__ ridx, const int* __restrict__ cnt, int t)
{
    __shared__ short As[2][GTM * TK];   // 2 x 32 KiB
    __shared__ short Bs[2][GTN * TK];   // 2 x 32 KiB
    const int n_act = cnt[t];
    const int tid  = threadIdx.x;
    const int wave = tid >> 6, lane = tid & 63;
    const int wm2 = wave >> 2, wn4 = wave & 3;   // wave -> 128-row half x 64-col quarter
    const int colq = lane & 15, q = lane >> 4;
    const int lrow8 = lane >> 3;
    const int lk    = (((lane & 7) ^ lrow8) * 8);   // pre-swizzled source offset
    const int xq = colq & 7;
    const int abase = (wm2 * 128 + colq) * TK;   // shorts
    const int bbase = (wn4 * 64  + colq) * TK;   // shorts

    // XCD-rectangle swizzle (grid is 16x16 for all gates_k launches).
    int bx, byS;
    {
        const int lin  = (int)blockIdx.x + 16 * (int)blockIdx.y;  // hw order
        const int xcd  = lin & 7;          // round-robin XCD assignment
        const int slot = lin >> 3;         // 0..31 within this XCD
        bx  = (xcd & 1) * 8 + (slot & 7);  // 8 consecutive x per XCD
        byS = (xcd >> 1) * 4 + (slot >> 3);// 4 consecutive y per XCD
    }
    const int n0 = bx * GTN;

    for (int by = byS; by * GTM < n_act; by += 16) {
        const int m0 = by * GTM;

        // per-wave staged rows: wave*32 + it*8 + lrow8 (A and B share the map)
        int rows_[4];
        const short* gb[4];
#pragma unroll
        for (int it = 0; it < 4; ++it) {
            const int rr = wave * 32 + it * 8 + lrow8;
            rows_[it] = ridx[m0 + rr];
            gb[it] = B + (size_t)(n0 + rr) * KTOT + lk;
        }

        float4v acc[8][4];
#pragma unroll
        for (int i = 0; i < 8; ++i)
#pragma unroll
            for (int j = 0; j < 4; ++j) acc[i][j] = (float4v)0.f;

        auto stage = [&](int ki, int buf) {
            const int kk = ki * TK;
            const bool fromS = (kk < hidK);   // kernel-uniform branch
#pragma unroll
            for (int it = 0; it < 4; ++it) {
                const int dst = (wave * 32 + it * 8) * TK;
                const short* sa = fromS
                    ? (S  + (size_t)rows_[it] * HID    + kk + lk)
                    : (XB + (size_t)rows_[it] * IN_DIM + lk);
                __builtin_amdgcn_global_load_lds(
                    (const __attribute__((address_space(1))) void*)sa,
                    (__attribute__((address_space(3))) void*)(As[buf] + dst), 16, 0, 0);
                __builtin_amdgcn_global_load_lds(
                    (const __attribute__((address_space(1))) void*)(gb[it] + kk),
                    (__attribute__((address_space(3))) void*)(Bs[buf] + dst), 16, 0, 0);
            }
        };

        stage(0, 0);
        __syncthreads();   // drains prologue stage

        for (int ki = 0; ki < nK; ++ki) {
            const int cur = ki & 1;
            if (ki + 1 < nK) stage(ki + 1, cur ^ 1);   // issue BEFORE compute
            const short* Ac = As[cur];
            const short* Bc = Bs[cur];
#pragma unroll
            for (int c2 = 0; c2 < 2; ++c2) {
                const int xt = ((q + 4 * c2) ^ xq) << 3;
                short8 af[8], bf[4];
#pragma unroll
                for (int i = 0; i < 8; ++i)
                    af[i] = *(const short8*)(Ac + abase + i * (16 * TK) + xt);
#pragma unroll
                for (int j = 0; j < 4; ++j)
                    bf[j] = *(const short8*)(Bc + bbase + j * (16 * TK) + xt);
#pragma unroll
                for (int i = 0; i < 8; ++i)
#pragma unroll
                    for (int j = 0; j < 4; ++j)
                        acc[i][j] = __builtin_amdgcn_mfma_f32_16x16x32_bf16(af[i], bf[j], acc[i][j], 0, 0, 0);
            }
            // one barrier per K-step: lgkm (ds_reads) drained by MFMA deps,
            // vmcnt drained inside __syncthreads -> buf[cur^1] ready.
            __syncthreads();
        }

        // epilogue: per wave, cols n0 + wn4*64 .. +63 = one 64-col G-group
        // = all 4 gates of 16 hidden units (interleaved weight layout).
        const int G = bx * 4 + wn4;
        const int h = G * 16 + colq;
        const float bi  = bias_g[G * 64 +  0 + colq];
        const float bff = bias_g[G * 64 + 16 + colq];
        const float bc  = bias_g[G * 64 + 32 + colq];
        const float bo  = bias_g[G * 64 + 48 + colq];
#pragma unroll
        for (int i = 0; i < 8; ++i) {
            const int pbase = m0 + wm2 * 128 + i * 16 + q * 4;
#pragma unroll
            for (int r = 0; r < 4; ++r) {
                const int pos = pbase + r;
                if (pos < n_act) {
                    const int row = ridx[pos];
                    const float ig = sigmoidf_(acc[i][0][r] + bi);
                    const float fg = sigmoidf_(acc[i][1][r] + bff);
                    const float cg = tanhf_(acc[i][2][r] + bc);
                    const float og = sigmoidf_(acc[i][3][r] + bo);
                    const size_t ci = (size_t)row * HID + h;
                    const float c = first ? (ig * cg) : (fg * cell[ci] + ig * cg);
                    cell[ci] = c;
                    Sout[(size_t)row * HID + h] = f2bf(og * tanhf_(c));
                }
            }
        }
        // last K-iter ended in __syncthreads; epilogue touches no LDS;
        // next m-tile's stage(0,0) is followed by its own __syncthreads.
    }
}

// Single-m-tile gates (R10 form, split-A, 128^2) — used only inside tail_k.
__device__ __forceinline__ void gates_tile(
    short* As, short* Bs, int tid,
    const short* __restrict__ S, const short* __restrict__ XB,
    const short* __restrict__ B,
    const float* __restrict__ bias_g,
    float* __restrict__ cell, short* __restrict__ Sout,
    const int* __restrict__ ridx, int n_act, int m0, int bx)
{
    const int wave = tid >> 6, lane = tid & 63;
    const int wm = wave & 1, wn = wave >> 1;
    const int colq = lane & 15, q = lane >> 4;
    const int lrow8 = lane >> 3;
    const int lk    = (((lane & 7) ^ lrow8) * 8);
    const int n0 = bx * TN;

    int aoff[4][2], boff[4][2];
#pragma unroll
    for (int i = 0; i < 4; ++i) {
        const int Ra = wm * 64 + i * 16 + colq;
        const int Rb = wn * 64 + i * 16 + colq;
#pragma unroll
        for (int c2 = 0; c2 < 2; ++c2) {
            const int C = q + 4 * c2;
            aoff[i][c2] = Ra * TK + ((C ^ (Ra & 7)) << 3);
            boff[i][c2] = Rb * TK + ((C ^ (Rb & 7)) << 3);
        }
    }

    float4v acc[4][4];
#pragma unroll
    for (int i = 0; i < 4; ++i)
#pragma unroll
        for (int j = 0; j < 4; ++j) acc[i][j] = (float4v)0.f;

    const short* gaS[4];
    const short* gaX[4];
    const short* gb[4];
#pragma unroll
    for (int it = 0; it < 4; ++it) {
        const int rr = (wave * 4 + it) * 8;
        const int r0 = ridx[m0 + rr + lrow8];
        gaS[it] = S + (size_t)r0 * HID + lk;
        gaX[it] = XB + (size_t)r0 * IN_DIM + lk;
        gb[it]  = B + (size_t)(n0 + rr + lrow8) * KTOT + lk;
    }

    for (int ki = 0; ki < KTOT / TK; ++ki) {
        const bool fromS = (ki * TK < HID);
#pragma unroll
        for (int it = 0; it < 4; ++it) {
            const int rr = (wave * 4 + it) * 8;
            const short* a0 = fromS ? gaS[it] : gaX[it];
            __builtin_amdgcn_global_load_lds(
                (const __attribute__((address_space(1))) void*)a0,
                (__attribute__((address_space(3))) void*)(As + rr * TK), 16, 0, 0);
            __builtin_amdgcn_global_load_lds(
                (const __attribute__((address_space(1))) void*)gb[it],
                (__attribute__((address_space(3))) void*)(Bs + rr * TK), 16, 0, 0);
            gaS[it] += TK; gb[it] += TK;
        }
        __syncthreads();
#pragma unroll
        for (int c2 = 0; c2 < 2; ++c2) {
            short8 af[4], bf[4];
#pragma unroll
            for (int i = 0; i < 4; ++i) {
                af[i] = *(const short8*)(As + aoff[i][c2]);
                bf[i] = *(const short8*)(Bs + boff[i][c2]);
            }
#pragma unroll
            for (int i = 0; i < 4; ++i)
#pragma unroll
                for (int j = 0; j < 4; ++j)
                    acc[i][j] = __builtin_amdgcn_mfma_f32_16x16x32_bf16(af[i], bf[j], acc[i][j], 0, 0, 0);
        }
        __syncthreads();
    }

    gates_epilogue(acc, m0, bx, wave, lane, 0, bias_g, cell, Sout, ridx, n_act);
    __syncthreads();   // protect As/Bs before caller's next tile
}

// Midfin — FINAL: TMF=16 (2 blocks/CU TLP) + 2-phase double-buffer +
// halt-dot fused into the GEMM + wave-ballot ordered compaction (R24:
// time/FETCH-neutral vs atomicAdd, kept for its single-atomic form).
// Wave w owns cols w*32..+31; all waves share the A fragment.
__device__ __forceinline__ void midfin_tile(
    short* As0, short* As1, short* Bs0, short* Bs1, int tid,
    const short* __restrict__ Snew, const short* __restrict__ P,
    const float* __restrict__ bias_p, const float* __restrict__ W_halt,
    const float* __restrict__ W2, const float* __restrict__ b2,
    float* __restrict__ outp, float* __restrict__ p_sum,
    const int* __restrict__ rprev, int* __restrict__ rnext,
    int* __restrict__ cnt, int t, int m0, int n_act)
{
    const int wave = tid >> 6, lane = tid & 63;
    const int colq = lane & 15, q = lane >> 4;
    const int lrow8 = lane >> 3;
    const int lk    = (((lane & 7) ^ lrow8) * 8);
    const int xq = colq & 7;

    float4v acc[2];
    acc[0] = (float4v)0.f; acc[1] = (float4v)0.f;
    float4v acc_h = (float4v)0.f;

    // per-lane source rows (rows beyond n_act read stale-but-in-range ridx
    // entries -> safe dummy gathers, results masked at finalize)
    const int arow_ = (wave < 2) ? rprev[m0 + wave * 8 + lrow8] : 0;
    const short* ga = Snew + (size_t)arow_ * HID + lk;
    const short* gbp[4];
#pragma unroll
    for (int g = 0; g < 4; ++g)
        gbp[g] = P + (size_t)(wave * 32 + g * 8 + lrow8) * HID + lk;
    const short* gbh[2];
#pragma unroll
    for (int l = 0; l < 2; ++l)
        gbh[l] = P + (size_t)(128 + l * 8 + lrow8) * HID + lk;

    auto stage = [&](int ks, short* Asb, short* Bsb) {
        const int k0 = ks * TK;
        if (wave < 2)   // wave-uniform: A rows wave*8..+7
            __builtin_amdgcn_global_load_lds(
                (const __attribute__((address_space(1))) void*)(ga + k0),
                (__attribute__((address_space(3))) void*)(Asb + (wave * 8) * TK), 16, 0, 0);
#pragma unroll
        for (int g = 0; g < 4; ++g)
            __builtin_amdgcn_global_load_lds(
                (const __attribute__((address_space(1))) void*)(gbp[g] + k0),
                (__attribute__((address_space(3))) void*)(Bsb + (wave * 32 + g * 8) * TK), 16, 0, 0);
        if (wave == 3)  // wave-uniform: halt rows 128..143
#pragma unroll
            for (int l = 0; l < 2; ++l)
                __builtin_amdgcn_global_load_lds(
                    (const __attribute__((address_space(1))) void*)(gbh[l] + k0),
                    (__attribute__((address_space(3))) void*)(Bsb + (128 + l * 8) * TK), 16, 0, 0);
    };

    stage(0, As0, Bs0);
    __syncthreads();   // drains prologue stage

    for (int ks = 0; ks < HID / TK; ++ks) {
        const int cur = ks & 1;
        if (ks + 1 < HID / TK)   // issue next stage BEFORE compute
            stage(ks + 1, cur ? As0 : As1, cur ? Bs0 : Bs1);
        const short* Asb = cur ? As1 : As0;
        const short* Bsb = cur ? Bs1 : Bs0;
#pragma unroll
        for (int c2 = 0; c2 < 2; ++c2) {
            const int xt = ((q + 4 * c2) ^ xq) << 3;
            const short8 af = *(const short8*)(Asb + colq * TK + xt);
            const short8 bf0 = *(const short8*)(Bsb + (wave * 32 + colq) * TK + xt);
            const short8 bf1 = *(const short8*)(Bsb + (wave * 32 + 16 + colq) * TK + xt);
            acc[0] = __builtin_amdgcn_mfma_f32_16x16x32_bf16(af, bf0, acc[0], 0, 0, 0);
            acc[1] = __builtin_amdgcn_mfma_f32_16x16x32_bf16(af, bf1, acc[1], 0, 0, 0);
            if (wave == 0) {   // halt fragment: B rows 128..143
                const short8 bh = *(const short8*)(Bsb + (128 + colq) * TK + xt);
                acc_h = __builtin_amdgcn_mfma_f32_16x16x32_bf16(af, bh, acc_h, 0, 0, 0);
            }
        }
        __syncthreads();   // reads retired (lgkm) + next stage landed (vmcnt)
    }

    // aliases over As0 (k-loop done; last barrier above protects)
    float* red  = (float*)As0;          // 64 floats: [w][q][r]
    float* hbuf = ((float*)As0) + 64;   // 16 floats

    // halt values: wave 0's col-0 lanes hold state.W_halt for row q*4+r
    if (wave == 0 && colq == 0) {
#pragma unroll
        for (int r = 0; r < 4; ++r)
            hbuf[q * 4 + r] = acc_h[r];
    }

    // relu + W2-dot over this wave's 32 cols, reduce over colq
    float pr[4];
#pragma unroll
    for (int r = 0; r < 4; ++r) pr[r] = 0.f;
#pragma unroll
    for (int nj = 0; nj < 2; ++nj) {
        const int col = wave * 32 + nj * 16 + colq;
        const float b = bias_p[col];
        const float w2 = W2[col];
#pragma unroll
        for (int r = 0; r < 4; ++r)
            pr[r] += fmaxf(acc[nj][r] + b, 0.f) * w2;
    }
#pragma unroll
    for (int r = 0; r < 4; ++r) {
        float v = pr[r];
        v += __shfl_down(v, 8, 16);
        v += __shfl_down(v, 4, 16);
        v += __shfl_down(v, 2, 16);
        v += __shfl_down(v, 1, 16);
        if (colq == 0)
            red[(wave * 4 + q) * 4 + r] = v;
    }
    __syncthreads();

    // finalize: lanes 0..15 of wave 0, one per row; ORDERED compaction.
    if (tid < TMF) {
        const int pos = m0 + tid;
        bool alive = false;
        int row = 0;
        if (pos < n_act) {
            const int lq = tid >> 2, r = tid & 3;
            float odot = 0.f;
#pragma unroll
            for (int w = 0; w < 4; ++w)
                odot += red[(w * 4 + lq) * 4 + r];
            row = rprev[pos];
            const float ov = sigmoidf_(odot + b2[0]);
            const float h  = sigmoidf_(hbuf[tid] + bias_p[OMID]);
            const float ps = p_sum[row];
            const float pn = ps + h;
            const bool fin = (pn >= 1.f - 1e-3f) || (t == MAX_ITER - 1);
            const float halt = fin ? (1.f - ps) : h;
            outp[row] += ov * halt;
            p_sum[row] = fin ? 1.f : pn;
            alive = !fin;
        }
        // ballot over active lanes (0..15); higher lanes contribute no bits.
        const unsigned long long m = __ballot(alive);
        int base = 0;
        if (tid == 0 && m)
            base = atomicAdd(&cnt[t + 1], __popcll(m));
        base = __shfl(base, 0);   // lane 0 is always active here
        if (alive) {
            const int off = __popcll(m & ((1ull << tid) - 1ull));
            astore(&rnext[base + off], row);
        }
    }
    __syncthreads();   // protect As/Bs aliases before caller reuses LDS
}

// Standalone midfin dispatch (steps 0..2): 512 blocks x 16-row tiles.
__global__ __launch_bounds__(256) void midfin_k(
    const short* __restrict__ Snew, const short* __restrict__ P,
    const float* __restrict__ bias_p, const float* __restrict__ W_halt,
    const float* __restrict__ W2, const float* __restrict__ b2,
    float* __restrict__ outp, float* __restrict__ p_sum,
    const int* __restrict__ rprev, int* __restrict__ rnext,
    int* __restrict__ cnt, int t)
{
    __shared__ short As[2][TMF * TK];   // 2 x 2 KiB
    __shared__ short Bs[2][NBH * TK];   // 2 x 18 KiB
    const int n_act = cnt[t];
    for (int tile = blockIdx.x; tile * TMF < n_act; tile += gridDim.x)
        midfin_tile(As[0], As[1], Bs[0], Bs[1], threadIdx.x,
                    Snew, P, bias_p, W_halt, W2, b2,
                    outp, p_sum, rprev, rnext, cnt, t, tile * TMF, n_act);
}

// Persistent 64-block tail: steps 3..7 (midfin+gates) with in-kernel
// barriers. For this data cnt[3]==0 so it exits after one gbar; full loop
// retained for arbitrary data.
__global__ __launch_bounds__(256) void tail_k(
    const short* __restrict__ Wg, const float* __restrict__ bias_g,
    const short* __restrict__ P, const float* __restrict__ bias_p,
    const float* __restrict__ W_halt, const float* __restrict__ W2,
    const float* __restrict__ b2,
    short* __restrict__ S0, short* __restrict__ S1,
    const short* __restrict__ XB,
    float* __restrict__ cell, float* __restrict__ outp,
    float* __restrict__ p_sum,
    int* __restrict__ ridx0, int* __restrict__ ridx1,
    int* __restrict__ cnt, int* __restrict__ bar)
{
    __shared__ short As[2][TM * TK];    // gates_tile uses As[0]/Bs[0] flat
    __shared__ short Bs[2][NBH * TK];   // (NBH*TK = 9216 >= TN*TK = 8192)
    const int tid = threadIdx.x;
    int phase = 0;
    int t = 3;
    while (true) {
        short* Snew = (t & 1) ? S0 : S1;        // state written by gates(t)
        const int* rprev = (t & 1) ? ridx1 : ridx0;  // L_t
        int* rnext = (t & 1) ? ridx0 : ridx1;        // L_{t+1}
        const int n = aload(&cnt[t]);
        for (int tile = blockIdx.x; tile * TMF < n; tile += gridDim.x)
            midfin_tile(As[0], As[1], Bs[0], Bs[1], tid,
                        Snew, P, bias_p, W_halt, W2, b2,
                        outp, p_sum, rprev, rnext, cnt, t, tile * TMF, n);
        if (t == MAX_ITER - 1) break;
        ++phase; gbar(bar, phase, tid);          // publish cnt[t+1], ridx, p_sum
        const int n1 = aload(&cnt[t + 1]);
        if (n1 == 0) break;                      // uniform across blocks
        {
            short* Sot = (t & 1) ? S1 : S0;
            const int ntiles = ((n1 + TM - 1) / TM) * (NGATES / TN);
            for (int e = blockIdx.x; e < ntiles; e += gridDim.x)
                gates_tile(As[0], Bs[0], tid, Snew, XB, Wg, bias_g, cell, Sot,
                           rnext, n1, (e >> 5) * TM, e & 31);
        }
        ++phase; gbar(bar, phase, tid);          // publish Sout, cell
        ++t;
    }
}

// Setup: x4 VECTORIZED weight packing (float4 in, short4 out).
// NOTE: S0/S1/cell are deliberately NOT initialized — at t=0 all rows are
// active, so gates(0) writes every state/cell entry before any read.
#define SETUP_XB4   (BATCH * IN_DIM / 4)
#define SETUP_WG4   (NGATES * (KTOT / 4))
#define SETUP_P4    (NP * (HID / 4))
#define SETUP_TOT4  (SETUP_XB4 + SETUP_WG4 + SETUP_P4)
__global__ __launch_bounds__(256) void setup_k(
    const float* __restrict__ x,
    const float* __restrict__ Whi, const float* __restrict__ Whf,
    const float* __restrict__ Whc, const float* __restrict__ Who,
    const float* __restrict__ Wxi, const float* __restrict__ Wxf,
    const float* __restrict__ Wxc, const float* __restrict__ Wxo,
    const float* __restrict__ bxi, const float* __restrict__ bhi,
    const float* __restrict__ bxf, const float* __restrict__ bhf,
    const float* __restrict__ bxc, const float* __restrict__ bhc,
    const float* __restrict__ bxo, const float* __restrict__ bho,
    const float* __restrict__ W1, const float* __restrict__ b1,
    const float* __restrict__ W_halt, const float* __restrict__ b_halt,
    short* __restrict__ XB,
    float* __restrict__ p_sum,
    int* __restrict__ ridx0, int* __restrict__ ridx1, int* __restrict__ cnt,
    int* __restrict__ bar, float* __restrict__ outp,
    short* __restrict__ Wg, float* __restrict__ bias_g,
    short* __restrict__ P, float* __restrict__ bias_p)
{
    int idx = blockIdx.x * 256 + threadIdx.x;
    if (idx < SETUP_XB4) {
        const int row = idx >> 4, k4 = (idx & 15) * 4;
        const float4f v = *(const float4f*)(x + row * IN_DIM + k4);
        short4v o;
#pragma unroll
        for (int e = 0; e < 4; ++e) o[e] = f2bf(v[e]);
        *(short4v*)(XB + row * IN_DIM + k4) = o;
        if (k4 == 0) {
            p_sum[row] = 0.f;
            outp[row] = 0.f;
            ridx0[row] = row;   // step 0: identity compaction
            ridx1[row] = 0;     // in-range dummies for padded tile reads
        }
        if (idx == 0) {
            for (int k = 0; k <= MAX_ITER; ++k) cnt[k] = (k == 0) ? BATCH : 0;
            bar[0] = 0;
        }
        return;
    }
    idx -= SETUP_XB4;
    if (idx < SETUP_WG4) {
        const int n = idx / (KTOT / 4), k4 = (idx - n * (KTOT / 4)) * 4;
        // interleaved layout: n = 64*G + 16*g + q  ->  gate g of hidden h=16*G+q
        const int G = n >> 6, g = (n >> 4) & 3, qq = n & 15;
        const int h = G * 16 + qq;
        const float* Wh = (g == 0) ? Whi : (g == 1) ? Whf : (g == 2) ? Whc : Who;
        const float* Wx = (g == 0) ? Wxi : (g == 1) ? Wxf : (g == 2) ? Wxc : Wxo;
        const float4f v = (k4 < HID)
            ? *(const float4f*)(Wh + h * HID + k4)
            : *(const float4f*)(Wx + h * IN_DIM + (k4 - HID));
        short4v o;
#pragma unroll
        for (int e = 0; e < 4; ++e) o[e] = f2bf(v[e]);
        *(short4v*)(Wg + (size_t)n * KTOT + k4) = o;
        if (k4 == 0) {
            const float* bx = (g == 0) ? bxi : (g == 1) ? bxf : (g == 2) ? bxc : bxo;
            const float* bh = (g == 0) ? bhi : (g == 1) ? bhf : (g == 2) ? bhc : bho;
            bias_g[n] = bx[h] + bh[h];
        }
        return;
    }
    idx -= SETUP_WG4;
    if (idx < SETUP_P4) {
        const int n = idx >> 8, k4 = (idx & 255) * 4;
        float4f v;
        if (n < OMID)      v = *(const float4f*)(W1 + n * HID + k4);
        else if (n == OMID) v = *(const float4f*)(W_halt + k4);
        else { v[0] = 0.f; v[1] = 0.f; v[2] = 0.f; v[3] = 0.f; }
        short4v o;
#pragma unroll
        for (int e = 0; e < 4; ++e) o[e] = f2bf(v[e]);
        *(short4v*)(P + (size_t)n * HID + k4) = o;
        if (k4 == 0) bias_p[n] = (n < OMID) ? b1[n] : (n == OMID ? b_halt[0] : 0.f);
    }
}

extern "C" void kernel_launch(void* const* d_in, const int* in_sizes, int n_in,
                              void* d_out, int out_size, void* d_ws, size_t ws_size,
                              hipStream_t stream) {
    const float* x    = (const float*)d_in[0];
    const float* Wxi  = (const float*)d_in[1];
    const float* bxi  = (const float*)d_in[2];
    const float* Whi  = (const float*)d_in[3];
    const float* bhi  = (const float*)d_in[4];
    const float* Wxf  = (const float*)d_in[5];
    const float* bxf  = (const float*)d_in[6];
    const float* Whf  = (const float*)d_in[7];
    const float* bhf  = (const float*)d_in[8];
    const float* Wxc  = (const float*)d_in[9];
    const float* bxc  = (const float*)d_in[10];
    const float* Whc  = (const float*)d_in[11];
    const float* bhc  = (const float*)d_in[12];
    const float* Wxo  = (const float*)d_in[13];
    const float* bxo  = (const float*)d_in[14];
    const float* Who  = (const float*)d_in[15];
    const float* bho  = (const float*)d_in[16];
    const float* W_halt = (const float*)d_in[17];
    const float* b_halt = (const float*)d_in[18];
    const float* W1   = (const float*)d_in[19];
    const float* b1   = (const float*)d_in[20];
    const float* W2   = (const float*)d_in[21];
    const float* b2   = (const float*)d_in[22];

    char* p = (char*)d_ws;
    auto carve = [&](size_t bytes) { char* r = p; p += (bytes + 255) & ~(size_t)255; return r; };
    short* S0     = (short*)carve((size_t)BATCH * HID * 2);
    short* S1     = (short*)carve((size_t)BATCH * HID * 2);
    short* XB     = (short*)carve((size_t)BATCH * IN_DIM * 2);
    short* Wg     = (short*)carve((size_t)NGATES * KTOT * 2);
    float* bias_g = (float*)carve((size_t)NGATES * 4);
    short* P      = (short*)carve((size_t)NP * HID * 2);
    float* bias_p = (float*)carve((size_t)NP * 4);
    float* cell   = (float*)carve((size_t)BATCH * HID * 4);
    float* p_sum  = (float*)carve((size_t)BATCH * 4);
    int*   ridx0  = (int*)carve((size_t)BATCH * 4);
    int*   ridx1  = (int*)carve((size_t)BATCH * 4);
    int*   cnt    = (int*)carve((size_t)(MAX_ITER + 1) * 4);
    int*   bar    = (int*)carve(256);
    float* outp   = (float*)d_out;

    setup_k<<<(SETUP_TOT4 + 255) / 256, 256, 0, stream>>>(
        x, Whi, Whf, Whc, Who, Wxi, Wxf, Wxc, Wxo,
        bxi, bhi, bxf, bhf, bxc, bhc, bxo, bho,
        W1, b1, W_halt, b_halt,
        XB, p_sum, ridx0, ridx1, cnt, bar, outp,
        Wg, bias_g, P, bias_p);

    // t=0: state==0 -> x-part only (1 k-iter from XB), cell write-only
    gates_k<<<dim3(16, 16), 512, 0, stream>>>(
        S0, XB, Wg + HID, bias_g, 1, 0, 1, cell, S1, ridx0, cnt, 0);
    midfin_k<<<512, 256, 0, stream>>>(
        S1, P, bias_p, W_halt, W2, b2, outp, p_sum, ridx0, ridx1, cnt, 0);
    // t=1: full batch
    gates_k<<<dim3(16, 16), 512, 0, stream>>>(
        S1, XB, Wg, bias_g, KTOT / TK, HID, 0, cell, S0, ridx1, cnt, 1);
    midfin_k<<<512, 256, 0, stream>>>(
        S0, P, bias_p, W_halt, W2, b2, outp, p_sum, ridx1, ridx0, cnt, 1);
    // t=2: ~half batch
    gates_k<<<dim3(16, 16), 512, 0, stream>>>(
        S0, XB, Wg, bias_g, KTOT / TK, HID, 0, cell, S1, ridx0, cnt, 2);
    midfin_k<<<512, 256, 0, stream>>>(
        S1, P, bias_p, W_halt, W2, b2, outp, p_sum, ridx0, ridx1, cnt, 2);
    // steps 3..7 (empty for this data) in one persistent 64-block kernel
    tail_k<<<TAILB, 256, 0, stream>>>(
        Wg, bias_g, P, bias_p, W_halt, W2, b2,
        S0, S1, XB, cell, outp, p_sum, ridx0, ridx1, cnt, bar);
}